// Round 9
// baseline (1632.591 us; speedup 1.0000x reference)
//
#include <hip/hip_runtime.h>
#include <math.h>

#define DIMN    200
#define RSTRIDE 224          // padded row stride: 448B = 7 x 64B lines (aligned A-chunks)
#define NNODES  100000
#define NREL    500
#define NEDGES  200000
#define TSTEPS  3
#define KSTEPS  7            // K padded 200 -> 224 = 7*32
#define NB16    16           // N padded 200 -> 256
#define WPK_ELEMS (KSTEPS * NB16 * 64 * 8)   // 57344 bf16 per weight
#define SCAN_B  1024

typedef float  v4f  __attribute__((ext_vector_type(4)));
typedef __bf16 v8bf __attribute__((ext_vector_type(8)));

// R7: fragment mirror arrays removed. MFMA A-operand mapping for 16x16x32
// (lane l: row = l&15, k = s*32 + (l>>4)*8 + j) is served directly from
// row-major stride-224 tables; cols 200-223 are zero so the s=6 step needs
// no predication (zero A x zero W contributes nothing).

// ---------------- prologue l2norm: fp32 rows -> bf16 stride-224 rows (zero pad) ----------------
__launch_bounds__(256)
__global__ void l2norm_pro(const float* __restrict__ in, __bf16* __restrict__ out, int nrows)
{
    int idx  = blockIdx.x * 256 + threadIdx.x;
    int node = idx >> 5;
    int ch   = idx & 31;
    if (node >= nrows) return;
    float v[8] = {};
    if (ch < 25) {
        const float4* p = (const float4*)(in + (size_t)node * DIMN + ch * 8);
        float4 f0 = p[0], f1 = p[1];
        v[0]=f0.x; v[1]=f0.y; v[2]=f0.z; v[3]=f0.w;
        v[4]=f1.x; v[5]=f1.y; v[6]=f1.z; v[7]=f1.w;
    }
    float ss = 0.0f;
    #pragma unroll
    for (int k = 0; k < 8; ++k) ss += v[k] * v[k];
    #pragma unroll
    for (int off = 16; off; off >>= 1) ss += __shfl_xor(ss, off, 64);
    float s = 1.0f / fmaxf(sqrtf(ss), 1e-12f);
    if (ch < 28) {
        v8bf o;
        #pragma unroll
        for (int k = 0; k < 8; ++k) o[k] = (ch < 25) ? (__bf16)(v[k] * s) : (__bf16)0.0f;
        *(v8bf*)(out + (size_t)node * RSTRIDE + ch * 8) = o;
    }
}

// ---------------- batched CSR build over (t,node) super-nodes (R6 proven) ----------------
__launch_bounds__(256)
__global__ void edge_hist3(const int* __restrict__ edges, int* __restrict__ counts)
{
    int e = blockIdx.x * 256 + threadIdx.x;
    if (e < TSTEPS * NEDGES) {
        int t = e / NEDGES;
        atomicAdd(&counts[t * NNODES + edges[(size_t)e * 3 + 2]], 1);
    }
}

__launch_bounds__(SCAN_B)
__global__ void scan1(const int* __restrict__ counts, int* __restrict__ tmp,
                      int* __restrict__ bsum, int n)
{
    __shared__ int sh[SCAN_B];
    int i = blockIdx.x * SCAN_B + threadIdx.x;
    int v = (i < n) ? counts[i] : 0;
    sh[threadIdx.x] = v;
    __syncthreads();
    for (int off = 1; off < SCAN_B; off <<= 1) {
        int t = (threadIdx.x >= off) ? sh[threadIdx.x - off] : 0;
        __syncthreads();
        sh[threadIdx.x] += t;
        __syncthreads();
    }
    if (i < n) tmp[i] = sh[threadIdx.x];
    if (threadIdx.x == SCAN_B - 1) bsum[blockIdx.x] = sh[threadIdx.x];
}

__launch_bounds__(SCAN_B)
__global__ void scan2(int* __restrict__ bsum, int nb)
{
    __shared__ int sh[SCAN_B];
    int v = (threadIdx.x < nb) ? bsum[threadIdx.x] : 0;
    sh[threadIdx.x] = v;
    __syncthreads();
    for (int off = 1; off < SCAN_B; off <<= 1) {
        int t = (threadIdx.x >= off) ? sh[threadIdx.x - off] : 0;
        __syncthreads();
        sh[threadIdx.x] += t;
        __syncthreads();
    }
    if (threadIdx.x < nb) bsum[threadIdx.x] = sh[threadIdx.x] - v;
}

__launch_bounds__(SCAN_B)
__global__ void scan3(const int* __restrict__ tmp, const int* __restrict__ bsum,
                      int* __restrict__ offs, int n)
{
    int i = blockIdx.x * SCAN_B + threadIdx.x;
    if (i < n) offs[i + 1] = tmp[i] + bsum[blockIdx.x];
    if (i == 0) offs[0] = 0;
}

__launch_bounds__(256)
__global__ void edge_fill3(const int* __restrict__ edges, const int* __restrict__ offs,
                           int* __restrict__ cursor, int2* __restrict__ sorted)
{
    int e = blockIdx.x * 256 + threadIdx.x;
    if (e >= TSTEPS * NEDGES) return;
    int t = e / NEDGES;
    int s = edges[(size_t)e * 3 + 0];
    int r = edges[(size_t)e * 3 + 1];
    int d = edges[(size_t)e * 3 + 2];
    int sn = t * NNODES + d;
    int p = offs[sn] + atomicAdd(&cursor[sn], 1);
    sorted[p] = make_int2(s, r);
}

// ---------------- aggregate: S = segsum(x[src] + r[rel]) / max(deg,1) -> stride-224 rows ----------------
__launch_bounds__(256)
__global__ void agg_S(const int* __restrict__ offs, const int2* __restrict__ sorted,
                      const __bf16* __restrict__ XR, const __bf16* __restrict__ RnR,
                      __bf16* __restrict__ SR, int nnodes)
{
    int wave = (int)((blockIdx.x * blockDim.x + threadIdx.x) >> 6);
    int lane = threadIdx.x & 63;
    if (wave >= nnodes) return;
    int beg = offs[wave], end = offs[wave + 1];
    int ch = lane & 31;
    bool act = ch < 25;

    float acc[8] = {};
    for (int e = beg; e < end; ++e) {
        int2 sr = sorted[e];
        const __bf16* base = (lane < 32) ? (XR + (size_t)sr.x * RSTRIDE)
                                         : (RnR + (size_t)sr.y * RSTRIDE);
        v8bf v = {};
        if (act) v = *(const v8bf*)(base + ch * 8);
        #pragma unroll
        for (int k = 0; k < 8; ++k) acc[k] += (float)v[k];
    }
    #pragma unroll
    for (int k = 0; k < 8; ++k) acc[k] += __shfl_xor(acc[k], 32, 64);

    float rdeg = 1.0f / fmaxf((float)(end - beg), 1.0f);
    if (lane < 32 && ch < 28) {
        v8bf o;
        #pragma unroll
        for (int k = 0; k < 8; ++k) o[k] = act ? (__bf16)(acc[k] * rdeg) : (__bf16)0.0f;
        *(v8bf*)(SR + (size_t)wave * RSTRIDE + ch * 8) = o;
    }
}

// ---------------- weight pack: fp32 W[200x200] -> bf16, K-steps contiguous per (nb,lane) ----------------
// elem offset = ((nb*64 + lane)*7 + s)*8  -> GEMM B load = base + s*16B immediate.
__launch_bounds__(256)
__global__ void pack_w(const float* __restrict__ W0, const float* __restrict__ W1,
                       const float* __restrict__ W2, const float* __restrict__ W3,
                       const float* __restrict__ W4, __bf16* __restrict__ out)
{
    int id = blockIdx.x * 256 + threadIdx.x;
    const int nchunk = KSTEPS * NB16 * 64;        // 7168
    if (id >= 5 * nchunk) return;
    int wi = id / nchunk;
    int c  = id % nchunk;
    const float* W = wi == 0 ? W0 : wi == 1 ? W1 : wi == 2 ? W2 : wi == 3 ? W3 : W4;
    int nb   = c / 448;
    int rem  = c - nb * 448;
    int lane = rem / 7;
    int s    = rem - lane * 7;
    int kbase = s * 32 + (lane >> 4) * 8;
    int n     = nb * 16 + (lane & 15);
    __bf16* dst = out + (size_t)wi * WPK_ELEMS + (size_t)c * 8;
    #pragma unroll
    for (int j = 0; j < 8; ++j) {
        int k = kbase + j;
        float v = (k < DIMN && n < DIMN) ? W[k * DIMN + n] : 0.0f;
        dst[j] = (__bf16)v;
    }
}

// ---------------- G1: Out = A1@W1 + A2@W2 ; BM=64, 8 waves x ni=2, row-major A ----------------
__launch_bounds__(512)
__global__ void gemm_dual(const __bf16* __restrict__ A1, const __bf16* __restrict__ W1,
                          const __bf16* __restrict__ A2, const __bf16* __restrict__ W2,
                          __bf16* __restrict__ OutR, int M)
{
    const int tid  = threadIdx.x;
    const int w    = tid >> 6;          // 0..7
    const int lane = tid & 63;
    const int rlo  = lane & 15;
    const int g8   = lane >> 4;
    const int bm   = blockIdx.x * 64;

    __shared__ __bf16 T[64][264];

    v4f acc[4][2];
    #pragma unroll
    for (int mi = 0; mi < 4; ++mi)
        #pragma unroll
        for (int ni = 0; ni < 2; ++ni)
            acc[mi][ni] = (v4f){0.f, 0.f, 0.f, 0.f};

    const __bf16* a1p[4];
    const __bf16* a2p[4];
    #pragma unroll
    for (int mi = 0; mi < 4; ++mi) {
        int rr = bm + mi * 16 + rlo;
        if (rr >= M) rr = M - 1;                // clamp: outputs masked on emit
        a1p[mi] = A1 + (size_t)rr * RSTRIDE + g8 * 8;
        a2p[mi] = A2 + (size_t)rr * RSTRIDE + g8 * 8;
    }
    const __bf16* b1p[2];
    const __bf16* b2p[2];
    #pragma unroll
    for (int ni = 0; ni < 2; ++ni) {
        size_t bo = ((size_t)(w * 2 + ni) * 448 + lane * 7) * 8;
        b1p[ni] = W1 + bo;
        b2p[ni] = W2 + bo;
    }

    #pragma unroll
    for (int s = 0; s < KSTEPS; ++s) {
        v8bf b1[2], b2[2];
        #pragma unroll
        for (int ni = 0; ni < 2; ++ni) {
            b1[ni] = *(const v8bf*)(b1p[ni] + s * 8);
            b2[ni] = *(const v8bf*)(b2p[ni] + s * 8);
        }
        #pragma unroll
        for (int mi = 0; mi < 4; ++mi) {
            v8bf a1 = *(const v8bf*)(a1p[mi] + s * 32);
            v8bf a2 = *(const v8bf*)(a2p[mi] + s * 32);
            #pragma unroll
            for (int ni = 0; ni < 2; ++ni)
                acc[mi][ni] = __builtin_amdgcn_mfma_f32_16x16x32_bf16(a1, b1[ni], acc[mi][ni], 0, 0, 0);
            #pragma unroll
            for (int ni = 0; ni < 2; ++ni)
                acc[mi][ni] = __builtin_amdgcn_mfma_f32_16x16x32_bf16(a2, b2[ni], acc[mi][ni], 0, 0, 0);
        }
    }

    // D -> LDS tile (row = mi*16 + g8*4 + reg, col = w*32 + ni*16 + rlo)
    #pragma unroll
    for (int mi = 0; mi < 4; ++mi)
        #pragma unroll
        for (int reg = 0; reg < 4; ++reg)
            #pragma unroll
            for (int ni = 0; ni < 2; ++ni)
                T[mi * 16 + g8 * 4 + reg][w * 32 + ni * 16 + rlo] = (__bf16)acc[mi][ni][reg];
    __syncthreads();

    // row emit: 64 rows * 28 chunks = 1792 (cols 200-223 are zero via weight pad)
    #pragma unroll
    for (int j = 0; j < 4; ++j) {
        int it = tid + j * 512;
        if (it < 1792) {
            int row = it / 28, ch = it - row * 28;
            int gr = bm + row;
            if (gr < M)
                *(v8bf*)(OutR + (size_t)gr * RSTRIDE + ch * 8) = *(const v8bf*)&T[row][ch * 8];
        }
    }
}

// ---------------- G2 mega: cur = l2norm(A1@W1 + A2@W2); gate = sigmoid(A3@W3 + bias);
//                  h' = l2norm(gate*cur + (1-gate)*h); A3 = HR (own rows, in-place safe)
__launch_bounds__(512)
__global__ void gemm_mega(const __bf16* __restrict__ A1, const __bf16* __restrict__ W1,
                          const __bf16* __restrict__ A2, const __bf16* __restrict__ W2,
                          __bf16* __restrict__ HR, const __bf16* __restrict__ W3,
                          const float* __restrict__ Bias,
                          float* __restrict__ DoutF, int M, int finalStep)
{
    const int tid  = threadIdx.x;
    const int w    = tid >> 6;          // 0..7
    const int lane = tid & 63;
    const int rlo  = lane & 15;
    const int g8   = lane >> 4;
    const int bm   = blockIdx.x * 32;

    __shared__ __bf16 T[32][264];
    __shared__ float  rsq1[32][8];
    __shared__ float  rsq2[32][8];

    v4f acc1[2][2], acc2[2][2];
    #pragma unroll
    for (int mi = 0; mi < 2; ++mi)
        #pragma unroll
        for (int ni = 0; ni < 2; ++ni) {
            acc1[mi][ni] = (v4f){0.f, 0.f, 0.f, 0.f};
            acc2[mi][ni] = (v4f){0.f, 0.f, 0.f, 0.f};
        }

    const __bf16* a1p[2];
    const __bf16* a2p[2];
    const __bf16* a3p[2];
    #pragma unroll
    for (int mi = 0; mi < 2; ++mi) {
        int rr = bm + mi * 16 + rlo;
        if (rr >= M) rr = M - 1;
        a1p[mi] = A1 + (size_t)rr * RSTRIDE + g8 * 8;
        a2p[mi] = A2 + (size_t)rr * RSTRIDE + g8 * 8;
        a3p[mi] = HR + (size_t)rr * RSTRIDE + g8 * 8;
    }
    const __bf16* b1p[2];
    const __bf16* b2p[2];
    const __bf16* b3p[2];
    #pragma unroll
    for (int ni = 0; ni < 2; ++ni) {
        size_t bo = ((size_t)(w * 2 + ni) * 448 + lane * 7) * 8;
        b1p[ni] = W1 + bo;
        b2p[ni] = W2 + bo;
        b3p[ni] = W3 + bo;
    }

    #pragma unroll
    for (int s = 0; s < KSTEPS; ++s) {
        v8bf b1[2], b2[2], b3[2];
        #pragma unroll
        for (int ni = 0; ni < 2; ++ni) {
            b1[ni] = *(const v8bf*)(b1p[ni] + s * 8);
            b2[ni] = *(const v8bf*)(b2p[ni] + s * 8);
            b3[ni] = *(const v8bf*)(b3p[ni] + s * 8);
        }
        #pragma unroll
        for (int mi = 0; mi < 2; ++mi) {
            v8bf a1 = *(const v8bf*)(a1p[mi] + s * 32);
            v8bf a2 = *(const v8bf*)(a2p[mi] + s * 32);
            v8bf a3 = *(const v8bf*)(a3p[mi] + s * 32);
            #pragma unroll
            for (int ni = 0; ni < 2; ++ni)
                acc1[mi][ni] = __builtin_amdgcn_mfma_f32_16x16x32_bf16(a1, b1[ni], acc1[mi][ni], 0, 0, 0);
            #pragma unroll
            for (int ni = 0; ni < 2; ++ni)
                acc1[mi][ni] = __builtin_amdgcn_mfma_f32_16x16x32_bf16(a2, b2[ni], acc1[mi][ni], 0, 0, 0);
            #pragma unroll
            for (int ni = 0; ni < 2; ++ni)
                acc2[mi][ni] = __builtin_amdgcn_mfma_f32_16x16x32_bf16(a3, b3[ni], acc2[mi][ni], 0, 0, 0);
        }
    }

    // cur row sums-of-squares (cols >= 200 are zero via weight padding)
    #pragma unroll
    for (int mi = 0; mi < 2; ++mi)
        #pragma unroll
        for (int reg = 0; reg < 4; ++reg) {
            float ss = 0.0f;
            #pragma unroll
            for (int ni = 0; ni < 2; ++ni) ss += acc1[mi][ni][reg] * acc1[mi][ni][reg];
            ss += __shfl_xor(ss, 1, 64);
            ss += __shfl_xor(ss, 2, 64);
            ss += __shfl_xor(ss, 4, 64);
            ss += __shfl_xor(ss, 8, 64);
            if (rlo == 0) rsq1[mi * 16 + g8 * 4 + reg][w] = ss;
        }
    // stage h rows into T (overwritten only after blend completes)
    #pragma unroll
    for (int j = 0; j < 2; ++j) {
        int it = tid + j * 512;
        if (it < 800) {
            int row = it / 25, ch = it - row * 25;
            int gr = bm + row;
            v8bf hv = {};
            if (gr < M) hv = *(const v8bf*)(HR + (size_t)gr * RSTRIDE + ch * 8);
            *(v8bf*)&T[row][ch * 8] = hv;
        }
    }
    __syncthreads();

    // blend: v = gate*cur + (1-gate)*h  (store into acc1), second row reduce
    #pragma unroll
    for (int mi = 0; mi < 2; ++mi)
        #pragma unroll
        for (int reg = 0; reg < 4; ++reg) {
            int rl = mi * 16 + g8 * 4 + reg;
            float tot = rsq1[rl][0] + rsq1[rl][1] + rsq1[rl][2] + rsq1[rl][3]
                      + rsq1[rl][4] + rsq1[rl][5] + rsq1[rl][6] + rsq1[rl][7];
            float sc1 = 1.0f / fmaxf(sqrtf(tot), 1e-12f);
            float ss = 0.0f;
            #pragma unroll
            for (int ni = 0; ni < 2; ++ni) {
                int c = w * 32 + ni * 16 + rlo;
                float v = 0.0f;
                if (c < DIMN) {
                    float cur = acc1[mi][ni][reg] * sc1;
                    float gg  = 1.0f / (1.0f + __expf(-(acc2[mi][ni][reg] + Bias[c])));
                    float hh  = (float)T[rl][c];
                    v = gg * cur + (1.0f - gg) * hh;
                }
                acc1[mi][ni][reg] = v;
                ss += v * v;
            }
            ss += __shfl_xor(ss, 1, 64);
            ss += __shfl_xor(ss, 2, 64);
            ss += __shfl_xor(ss, 4, 64);
            ss += __shfl_xor(ss, 8, 64);
            if (rlo == 0) rsq2[rl][w] = ss;
        }
    __syncthreads();

    // final scale -> T (overwrites staged h; all h reads completed before barrier above)
    #pragma unroll
    for (int mi = 0; mi < 2; ++mi)
        #pragma unroll
        for (int reg = 0; reg < 4; ++reg) {
            int rl = mi * 16 + g8 * 4 + reg;
            float tot = rsq2[rl][0] + rsq2[rl][1] + rsq2[rl][2] + rsq2[rl][3]
                      + rsq2[rl][4] + rsq2[rl][5] + rsq2[rl][6] + rsq2[rl][7];
            float sc2 = 1.0f / fmaxf(sqrtf(tot), 1e-12f);
            #pragma unroll
            for (int ni = 0; ni < 2; ++ni) {
                int c = w * 32 + ni * 16 + rlo;
                T[rl][c] = (__bf16)(acc1[mi][ni][reg] * sc2);
            }
        }
    __syncthreads();

    if (!finalStep) {
        // h' rows: 32 rows * 28 chunks = 896 (cols 200-223 zero)
        #pragma unroll
        for (int j = 0; j < 2; ++j) {
            int it = tid + j * 512;
            if (it < 896) {
                int row = it / 28, ch = it - row * 28;
                int gr = bm + row;
                if (gr < M)
                    *(v8bf*)(HR + (size_t)gr * RSTRIDE + ch * 8) = *(const v8bf*)&T[row][ch * 8];
            }
        }
    } else {
        // fp32 output rows (stride DIMN)
        #pragma unroll
        for (int j = 0; j < 2; ++j) {
            int it = tid + j * 512;
            if (it < 800) {
                int row = it / 25, ch = it - row * 25;
                int gr = bm + row;
                if (gr < M) {
                    v8bf o = *(const v8bf*)&T[row][ch * 8];
                    float4* q0 = (float4*)(DoutF + (size_t)gr * DIMN + ch * 8);
                    q0[0] = make_float4((float)o[0], (float)o[1], (float)o[2], (float)o[3]);
                    q0[1] = make_float4((float)o[4], (float)o[5], (float)o[6], (float)o[7]);
                }
            }
        }
    }
}

extern "C" void kernel_launch(void* const* d_in, const int* in_sizes, int n_in,
                              void* d_out, int out_size, void* d_ws, size_t ws_size,
                              hipStream_t stream)
{
    const int*   edges = (const int*)  d_in[0];
    const float* ent   = (const float*)d_in[1];
    const float* relE  = (const float*)d_in[2];
    const float* Wm1   = (const float*)d_in[3];
    const float* Wl1   = (const float*)d_in[4];
    const float* Wm2   = (const float*)d_in[5];
    const float* Wl2   = (const float*)d_in[6];
    const float* Wtg   = (const float*)d_in[7];
    const float* bias  = (const float*)d_in[8];
    float* Dout = (float*)d_out;

    const size_t NM2 = (size_t)NNODES * RSTRIDE;

    __bf16* hR   = (__bf16*)d_ws;                      // h rows (stride 224)
    __bf16* SR   = hR + NM2;                           // S1/S2 rows
    __bf16* BR   = SR + NM2;                           // layer-1 out rows
    __bf16* RnR  = BR + NM2;                           // normalized relation rows
    __bf16* Wpk  = RnR + (size_t)NREL * RSTRIDE;       // 5 packed weights
    __bf16* pWm1 = Wpk + 0 * (size_t)WPK_ELEMS;
    __bf16* pWl1 = Wpk + 1 * (size_t)WPK_ELEMS;
    __bf16* pWm2 = Wpk + 2 * (size_t)WPK_ELEMS;
    __bf16* pWl2 = Wpk + 3 * (size_t)WPK_ELEMS;
    __bf16* pWtg = Wpk + 4 * (size_t)WPK_ELEMS;
    // batched CSR arrays over 3N super-nodes
    int*  counts = (int*)(Wpk + 5 * (size_t)WPK_ELEMS);
    int*  cursor = counts + TSTEPS * NNODES;
    int2* sorted = (int2*)(cursor + TSTEPS * NNODES);
    int*  offs   = (int*)(sorted + TSTEPS * NEDGES);
    int*  bsum   = offs + (TSTEPS * NNODES + 1);
    int*  stmp   = bsum + SCAN_B;

    dim3 blk(256);
    const int GD = (NNODES + 63) / 64;      // 1563 (dual, BM=64, 512 thr)
    const int GM = (NNODES + 31) / 32;      // 3125 (mega, BM=32, 512 thr)
    dim3 ngrid32((NNODES * 32 + 255) / 256);
    dim3 rgrid32((NREL * 32 + 255) / 256);
    dim3 agrid((NNODES + 3) / 4);
    dim3 egrid3((TSTEPS * NEDGES + 255) / 256);
    const int NTOT = TSTEPS * NNODES;               // 300000
    const int NSB  = (NTOT + SCAN_B - 1) / SCAN_B;  // 293

    // ---- weights + prologue norms ----
    pack_w<<<dim3((5 * KSTEPS * NB16 * 64 + 255) / 256), blk, 0, stream>>>(Wm1, Wl1, Wm2, Wl2, Wtg, Wpk);
    l2norm_pro<<<ngrid32, blk, 0, stream>>>(ent, hR, NNODES);
    l2norm_pro<<<rgrid32, blk, 0, stream>>>(relE, RnR, NREL);

    // ---- batched CSR build (all timesteps) ----
    hipMemsetAsync(counts, 0, 2 * NTOT * sizeof(int), stream);   // counts + cursor
    edge_hist3<<<egrid3, blk, 0, stream>>>(edges, counts);
    scan1<<<NSB, SCAN_B, 0, stream>>>(counts, stmp, bsum, NTOT);
    scan2<<<1, SCAN_B, 0, stream>>>(bsum, NSB);
    scan3<<<NSB, SCAN_B, 0, stream>>>(stmp, bsum, offs, NTOT);
    edge_fill3<<<egrid3, blk, 0, stream>>>(edges, offs, cursor, sorted);

    for (int t = 0; t < 3; ++t) {
        const int* offsT = offs + (size_t)t * NNODES;
        // ---- layer 1: aggregate in h-space, then dual-stream GEMM ----
        agg_S<<<agrid, blk, 0, stream>>>(offsT, sorted, hR, RnR, SR, NNODES);
        gemm_dual<<<GD, dim3(512), 0, stream>>>(SR, pWm1, hR, pWl1, BR, NNODES);
        // ---- layer 2 + gate + blend + norms (mega; HR in-place) ----
        agg_S<<<agrid, blk, 0, stream>>>(offsT, sorted, BR, RnR, SR, NNODES);
        gemm_mega<<<GM, dim3(512), 0, stream>>>(SR, pWm2, BR, pWl2, hR, pWtg, bias,
                                                Dout, NNODES, (t == 2) ? 1 : 0);
    }
}

// Round 10
// 1069.697 us; speedup vs baseline: 1.5262x; 1.5262x over previous
//
#include <hip/hip_runtime.h>
#include <math.h>

#define DIMN    200
#define RSTRIDE 224          // padded row stride: 448B = 7 x 64B lines (aligned A-chunks)
#define NNODES  100000
#define NREL    500
#define NEDGES  200000
#define TSTEPS  3
#define KSTEPS  7            // K padded 200 -> 224 = 7*32
#define NB16    16           // N padded 200 -> 256
#define WPK_ELEMS (KSTEPS * NB16 * 64 * 8)   // 57344 bf16 per weight
#define SCAN_B  1024

typedef float  v4f  __attribute__((ext_vector_type(4)));
typedef __bf16 v8bf __attribute__((ext_vector_type(8)));

// R9: R7's lane-contiguous-K weight pack was a 112B-stride scatter (64 txn/load,
// mega 124->294us). Restored R6 coalesced pack: chunk c = s*1024 + nb*64 + lane,
// so a wave's B-load is 1KB contiguous. Row-major A (R7) kept: frag mirror stays
// deleted (FETCH 89->67MB confirmed).

// ---------------- prologue l2norm: fp32 rows -> bf16 stride-224 rows (zero pad) ----------------
__launch_bounds__(256)
__global__ void l2norm_pro(const float* __restrict__ in, __bf16* __restrict__ out, int nrows)
{
    int idx  = blockIdx.x * 256 + threadIdx.x;
    int node = idx >> 5;
    int ch   = idx & 31;
    if (node >= nrows) return;
    float v[8] = {};
    if (ch < 25) {
        const float4* p = (const float4*)(in + (size_t)node * DIMN + ch * 8);
        float4 f0 = p[0], f1 = p[1];
        v[0]=f0.x; v[1]=f0.y; v[2]=f0.z; v[3]=f0.w;
        v[4]=f1.x; v[5]=f1.y; v[6]=f1.z; v[7]=f1.w;
    }
    float ss = 0.0f;
    #pragma unroll
    for (int k = 0; k < 8; ++k) ss += v[k] * v[k];
    #pragma unroll
    for (int off = 16; off; off >>= 1) ss += __shfl_xor(ss, off, 64);
    float s = 1.0f / fmaxf(sqrtf(ss), 1e-12f);
    if (ch < 28) {
        v8bf o;
        #pragma unroll
        for (int k = 0; k < 8; ++k) o[k] = (ch < 25) ? (__bf16)(v[k] * s) : (__bf16)0.0f;
        *(v8bf*)(out + (size_t)node * RSTRIDE + ch * 8) = o;
    }
}

// ---------------- batched CSR build over (t,node) super-nodes (R6 proven) ----------------
__launch_bounds__(256)
__global__ void edge_hist3(const int* __restrict__ edges, int* __restrict__ counts)
{
    int e = blockIdx.x * 256 + threadIdx.x;
    if (e < TSTEPS * NEDGES) {
        int t = e / NEDGES;
        atomicAdd(&counts[t * NNODES + edges[(size_t)e * 3 + 2]], 1);
    }
}

__launch_bounds__(SCAN_B)
__global__ void scan1(const int* __restrict__ counts, int* __restrict__ tmp,
                      int* __restrict__ bsum, int n)
{
    __shared__ int sh[SCAN_B];
    int i = blockIdx.x * SCAN_B + threadIdx.x;
    int v = (i < n) ? counts[i] : 0;
    sh[threadIdx.x] = v;
    __syncthreads();
    for (int off = 1; off < SCAN_B; off <<= 1) {
        int t = (threadIdx.x >= off) ? sh[threadIdx.x - off] : 0;
        __syncthreads();
        sh[threadIdx.x] += t;
        __syncthreads();
    }
    if (i < n) tmp[i] = sh[threadIdx.x];
    if (threadIdx.x == SCAN_B - 1) bsum[blockIdx.x] = sh[threadIdx.x];
}

__launch_bounds__(SCAN_B)
__global__ void scan2(int* __restrict__ bsum, int nb)
{
    __shared__ int sh[SCAN_B];
    int v = (threadIdx.x < nb) ? bsum[threadIdx.x] : 0;
    sh[threadIdx.x] = v;
    __syncthreads();
    for (int off = 1; off < SCAN_B; off <<= 1) {
        int t = (threadIdx.x >= off) ? sh[threadIdx.x - off] : 0;
        __syncthreads();
        sh[threadIdx.x] += t;
        __syncthreads();
    }
    if (threadIdx.x < nb) bsum[threadIdx.x] = sh[threadIdx.x] - v;
}

__launch_bounds__(SCAN_B)
__global__ void scan3(const int* __restrict__ tmp, const int* __restrict__ bsum,
                      int* __restrict__ offs, int n)
{
    int i = blockIdx.x * SCAN_B + threadIdx.x;
    if (i < n) offs[i + 1] = tmp[i] + bsum[blockIdx.x];
    if (i == 0) offs[0] = 0;
}

__launch_bounds__(256)
__global__ void edge_fill3(const int* __restrict__ edges, const int* __restrict__ offs,
                           int* __restrict__ cursor, int2* __restrict__ sorted)
{
    int e = blockIdx.x * 256 + threadIdx.x;
    if (e >= TSTEPS * NEDGES) return;
    int t = e / NEDGES;
    int s = edges[(size_t)e * 3 + 0];
    int r = edges[(size_t)e * 3 + 1];
    int d = edges[(size_t)e * 3 + 2];
    int sn = t * NNODES + d;
    int p = offs[sn] + atomicAdd(&cursor[sn], 1);
    sorted[p] = make_int2(s, r);
}

// ---------------- aggregate: S = segsum(x[src] + r[rel]) / max(deg,1) -> stride-224 rows ----------------
__launch_bounds__(256)
__global__ void agg_S(const int* __restrict__ offs, const int2* __restrict__ sorted,
                      const __bf16* __restrict__ XR, const __bf16* __restrict__ RnR,
                      __bf16* __restrict__ SR, int nnodes)
{
    int wave = (int)((blockIdx.x * blockDim.x + threadIdx.x) >> 6);
    int lane = threadIdx.x & 63;
    if (wave >= nnodes) return;
    int beg = offs[wave], end = offs[wave + 1];
    int ch = lane & 31;
    bool act = ch < 25;

    float acc[8] = {};
    for (int e = beg; e < end; ++e) {
        int2 sr = sorted[e];
        const __bf16* base = (lane < 32) ? (XR + (size_t)sr.x * RSTRIDE)
                                         : (RnR + (size_t)sr.y * RSTRIDE);
        v8bf v = {};
        if (act) v = *(const v8bf*)(base + ch * 8);
        #pragma unroll
        for (int k = 0; k < 8; ++k) acc[k] += (float)v[k];
    }
    #pragma unroll
    for (int k = 0; k < 8; ++k) acc[k] += __shfl_xor(acc[k], 32, 64);

    float rdeg = 1.0f / fmaxf((float)(end - beg), 1.0f);
    if (lane < 32 && ch < 28) {
        v8bf o;
        #pragma unroll
        for (int k = 0; k < 8; ++k) o[k] = act ? (__bf16)(acc[k] * rdeg) : (__bf16)0.0f;
        *(v8bf*)(SR + (size_t)wave * RSTRIDE + ch * 8) = o;
    }
}

// ---------------- weight pack (R6 coalesced): chunk c = s*1024 + nb*64 + lane ----------------
__launch_bounds__(256)
__global__ void pack_w(const float* __restrict__ W0, const float* __restrict__ W1,
                       const float* __restrict__ W2, const float* __restrict__ W3,
                       const float* __restrict__ W4, __bf16* __restrict__ out)
{
    int id = blockIdx.x * 256 + threadIdx.x;
    const int nchunk = KSTEPS * NB16 * 64;        // 7168
    if (id >= 5 * nchunk) return;
    int wi = id / nchunk;
    int c  = id % nchunk;
    const float* W = wi == 0 ? W0 : wi == 1 ? W1 : wi == 2 ? W2 : wi == 3 ? W3 : W4;
    int s    = c >> 10;
    int nb   = (c & 1023) >> 6;
    int lane = c & 63;
    int kbase = s * 32 + (lane >> 4) * 8;
    int n     = nb * 16 + (lane & 15);
    __bf16* dst = out + (size_t)wi * WPK_ELEMS + (size_t)c * 8;
    #pragma unroll
    for (int j = 0; j < 8; ++j) {
        int k = kbase + j;
        float v = (k < DIMN && n < DIMN) ? W[k * DIMN + n] : 0.0f;
        dst[j] = (__bf16)v;
    }
}

// ---------------- G1: Out = A1@W1 + A2@W2 ; BM=64, 8 waves x ni=2, row-major A ----------------
__launch_bounds__(512)
__global__ void gemm_dual(const __bf16* __restrict__ A1, const __bf16* __restrict__ W1,
                          const __bf16* __restrict__ A2, const __bf16* __restrict__ W2,
                          __bf16* __restrict__ OutR, int M)
{
    const int tid  = threadIdx.x;
    const int w    = tid >> 6;          // 0..7
    const int lane = tid & 63;
    const int rlo  = lane & 15;
    const int g8   = lane >> 4;
    const int bm   = blockIdx.x * 64;

    __shared__ __bf16 T[64][264];

    v4f acc[4][2];
    #pragma unroll
    for (int mi = 0; mi < 4; ++mi)
        #pragma unroll
        for (int ni = 0; ni < 2; ++ni)
            acc[mi][ni] = (v4f){0.f, 0.f, 0.f, 0.f};

    const __bf16* a1p[4];
    const __bf16* a2p[4];
    #pragma unroll
    for (int mi = 0; mi < 4; ++mi) {
        int rr = bm + mi * 16 + rlo;
        if (rr >= M) rr = M - 1;                // clamp: outputs masked on emit
        a1p[mi] = A1 + (size_t)rr * RSTRIDE + g8 * 8;
        a2p[mi] = A2 + (size_t)rr * RSTRIDE + g8 * 8;
    }
    // coalesced B: wave w covers col blocks w*2+ni; lane-consecutive 16B
    const __bf16* w1b = W1 + (size_t)(w * 2 * 64 + lane) * 8;
    const __bf16* w2b = W2 + (size_t)(w * 2 * 64 + lane) * 8;

    #pragma unroll
    for (int s = 0; s < KSTEPS; ++s) {
        v8bf b1[2], b2[2];
        #pragma unroll
        for (int ni = 0; ni < 2; ++ni) {
            size_t bo = ((size_t)s * NB16 * 64 + ni * 64) * 8;
            b1[ni] = *(const v8bf*)(w1b + bo);
            b2[ni] = *(const v8bf*)(w2b + bo);
        }
        #pragma unroll
        for (int mi = 0; mi < 4; ++mi) {
            v8bf a1 = *(const v8bf*)(a1p[mi] + s * 32);
            v8bf a2 = *(const v8bf*)(a2p[mi] + s * 32);
            #pragma unroll
            for (int ni = 0; ni < 2; ++ni)
                acc[mi][ni] = __builtin_amdgcn_mfma_f32_16x16x32_bf16(a1, b1[ni], acc[mi][ni], 0, 0, 0);
            #pragma unroll
            for (int ni = 0; ni < 2; ++ni)
                acc[mi][ni] = __builtin_amdgcn_mfma_f32_16x16x32_bf16(a2, b2[ni], acc[mi][ni], 0, 0, 0);
        }
    }

    // D -> LDS tile (row = mi*16 + g8*4 + reg, col = w*32 + ni*16 + rlo)
    #pragma unroll
    for (int mi = 0; mi < 4; ++mi)
        #pragma unroll
        for (int reg = 0; reg < 4; ++reg)
            #pragma unroll
            for (int ni = 0; ni < 2; ++ni)
                T[mi * 16 + g8 * 4 + reg][w * 32 + ni * 16 + rlo] = (__bf16)acc[mi][ni][reg];
    __syncthreads();

    // row emit: 64 rows * 28 chunks = 1792 (cols 200-223 are zero via weight pad)
    #pragma unroll
    for (int j = 0; j < 4; ++j) {
        int it = tid + j * 512;
        if (it < 1792) {
            int row = it / 28, ch = it - row * 28;
            int gr = bm + row;
            if (gr < M)
                *(v8bf*)(OutR + (size_t)gr * RSTRIDE + ch * 8) = *(const v8bf*)&T[row][ch * 8];
        }
    }
}

// ---------------- G2 mega: cur = l2norm(A1@W1 + A2@W2); gate = sigmoid(A3@W3 + bias);
//                  h' = l2norm(gate*cur + (1-gate)*h); A3 = HR (own rows, in-place safe)
__launch_bounds__(512)
__global__ void gemm_mega(const __bf16* __restrict__ A1, const __bf16* __restrict__ W1,
                          const __bf16* __restrict__ A2, const __bf16* __restrict__ W2,
                          __bf16* __restrict__ HR, const __bf16* __restrict__ W3,
                          const float* __restrict__ Bias,
                          float* __restrict__ DoutF, int M, int finalStep)
{
    const int tid  = threadIdx.x;
    const int w    = tid >> 6;          // 0..7
    const int lane = tid & 63;
    const int rlo  = lane & 15;
    const int g8   = lane >> 4;
    const int bm   = blockIdx.x * 32;

    __shared__ __bf16 T[32][264];
    __shared__ float  rsq1[32][8];
    __shared__ float  rsq2[32][8];

    v4f acc1[2][2], acc2[2][2];
    #pragma unroll
    for (int mi = 0; mi < 2; ++mi)
        #pragma unroll
        for (int ni = 0; ni < 2; ++ni) {
            acc1[mi][ni] = (v4f){0.f, 0.f, 0.f, 0.f};
            acc2[mi][ni] = (v4f){0.f, 0.f, 0.f, 0.f};
        }

    const __bf16* a1p[2];
    const __bf16* a2p[2];
    const __bf16* a3p[2];
    #pragma unroll
    for (int mi = 0; mi < 2; ++mi) {
        int rr = bm + mi * 16 + rlo;
        if (rr >= M) rr = M - 1;
        a1p[mi] = A1 + (size_t)rr * RSTRIDE + g8 * 8;
        a2p[mi] = A2 + (size_t)rr * RSTRIDE + g8 * 8;
        a3p[mi] = HR + (size_t)rr * RSTRIDE + g8 * 8;
    }
    const __bf16* w1b = W1 + (size_t)(w * 2 * 64 + lane) * 8;
    const __bf16* w2b = W2 + (size_t)(w * 2 * 64 + lane) * 8;
    const __bf16* w3b = W3 + (size_t)(w * 2 * 64 + lane) * 8;

    #pragma unroll
    for (int s = 0; s < KSTEPS; ++s) {
        v8bf b1[2], b2[2], b3[2];
        #pragma unroll
        for (int ni = 0; ni < 2; ++ni) {
            size_t bo = ((size_t)s * NB16 * 64 + ni * 64) * 8;
            b1[ni] = *(const v8bf*)(w1b + bo);
            b2[ni] = *(const v8bf*)(w2b + bo);
            b3[ni] = *(const v8bf*)(w3b + bo);
        }
        #pragma unroll
        for (int mi = 0; mi < 2; ++mi) {
            v8bf a1 = *(const v8bf*)(a1p[mi] + s * 32);
            v8bf a2 = *(const v8bf*)(a2p[mi] + s * 32);
            v8bf a3 = *(const v8bf*)(a3p[mi] + s * 32);
            #pragma unroll
            for (int ni = 0; ni < 2; ++ni)
                acc1[mi][ni] = __builtin_amdgcn_mfma_f32_16x16x32_bf16(a1, b1[ni], acc1[mi][ni], 0, 0, 0);
            #pragma unroll
            for (int ni = 0; ni < 2; ++ni)
                acc1[mi][ni] = __builtin_amdgcn_mfma_f32_16x16x32_bf16(a2, b2[ni], acc1[mi][ni], 0, 0, 0);
            #pragma unroll
            for (int ni = 0; ni < 2; ++ni)
                acc2[mi][ni] = __builtin_amdgcn_mfma_f32_16x16x32_bf16(a3, b3[ni], acc2[mi][ni], 0, 0, 0);
        }
    }

    // cur row sums-of-squares (cols >= 200 are zero via weight padding)
    #pragma unroll
    for (int mi = 0; mi < 2; ++mi)
        #pragma unroll
        for (int reg = 0; reg < 4; ++reg) {
            float ss = 0.0f;
            #pragma unroll
            for (int ni = 0; ni < 2; ++ni) ss += acc1[mi][ni][reg] * acc1[mi][ni][reg];
            ss += __shfl_xor(ss, 1, 64);
            ss += __shfl_xor(ss, 2, 64);
            ss += __shfl_xor(ss, 4, 64);
            ss += __shfl_xor(ss, 8, 64);
            if (rlo == 0) rsq1[mi * 16 + g8 * 4 + reg][w] = ss;
        }
    // stage h rows into T (overwritten only after blend completes)
    #pragma unroll
    for (int j = 0; j < 2; ++j) {
        int it = tid + j * 512;
        if (it < 800) {
            int row = it / 25, ch = it - row * 25;
            int gr = bm + row;
            v8bf hv = {};
            if (gr < M) hv = *(const v8bf*)(HR + (size_t)gr * RSTRIDE + ch * 8);
            *(v8bf*)&T[row][ch * 8] = hv;
        }
    }
    __syncthreads();

    // blend: v = gate*cur + (1-gate)*h  (store into acc1), second row reduce
    #pragma unroll
    for (int mi = 0; mi < 2; ++mi)
        #pragma unroll
        for (int reg = 0; reg < 4; ++reg) {
            int rl = mi * 16 + g8 * 4 + reg;
            float tot = rsq1[rl][0] + rsq1[rl][1] + rsq1[rl][2] + rsq1[rl][3]
                      + rsq1[rl][4] + rsq1[rl][5] + rsq1[rl][6] + rsq1[rl][7];
            float sc1 = 1.0f / fmaxf(sqrtf(tot), 1e-12f);
            float ss = 0.0f;
            #pragma unroll
            for (int ni = 0; ni < 2; ++ni) {
                int c = w * 32 + ni * 16 + rlo;
                float v = 0.0f;
                if (c < DIMN) {
                    float cur = acc1[mi][ni][reg] * sc1;
                    float gg  = 1.0f / (1.0f + __expf(-(acc2[mi][ni][reg] + Bias[c])));
                    float hh  = (float)T[rl][c];
                    v = gg * cur + (1.0f - gg) * hh;
                }
                acc1[mi][ni][reg] = v;
                ss += v * v;
            }
            ss += __shfl_xor(ss, 1, 64);
            ss += __shfl_xor(ss, 2, 64);
            ss += __shfl_xor(ss, 4, 64);
            ss += __shfl_xor(ss, 8, 64);
            if (rlo == 0) rsq2[rl][w] = ss;
        }
    __syncthreads();

    // final scale -> T (overwrites staged h; all h reads completed before barrier above)
    #pragma unroll
    for (int mi = 0; mi < 2; ++mi)
        #pragma unroll
        for (int reg = 0; reg < 4; ++reg) {
            int rl = mi * 16 + g8 * 4 + reg;
            float tot = rsq2[rl][0] + rsq2[rl][1] + rsq2[rl][2] + rsq2[rl][3]
                      + rsq2[rl][4] + rsq2[rl][5] + rsq2[rl][6] + rsq2[rl][7];
            float sc2 = 1.0f / fmaxf(sqrtf(tot), 1e-12f);
            #pragma unroll
            for (int ni = 0; ni < 2; ++ni) {
                int c = w * 32 + ni * 16 + rlo;
                T[rl][c] = (__bf16)(acc1[mi][ni][reg] * sc2);
            }
        }
    __syncthreads();

    if (!finalStep) {
        // h' rows: 32 rows * 28 chunks = 896 (cols 200-223 zero)
        #pragma unroll
        for (int j = 0; j < 2; ++j) {
            int it = tid + j * 512;
            if (it < 896) {
                int row = it / 28, ch = it - row * 28;
                int gr = bm + row;
                if (gr < M)
                    *(v8bf*)(HR + (size_t)gr * RSTRIDE + ch * 8) = *(const v8bf*)&T[row][ch * 8];
            }
        }
    } else {
        // fp32 output rows (stride DIMN)
        #pragma unroll
        for (int j = 0; j < 2; ++j) {
            int it = tid + j * 512;
            if (it < 800) {
                int row = it / 25, ch = it - row * 25;
                int gr = bm + row;
                if (gr < M) {
                    v8bf o = *(const v8bf*)&T[row][ch * 8];
                    float4* q0 = (float4*)(DoutF + (size_t)gr * DIMN + ch * 8);
                    q0[0] = make_float4((float)o[0], (float)o[1], (float)o[2], (float)o[3]);
                    q0[1] = make_float4((float)o[4], (float)o[5], (float)o[6], (float)o[7]);
                }
            }
        }
    }
}

extern "C" void kernel_launch(void* const* d_in, const int* in_sizes, int n_in,
                              void* d_out, int out_size, void* d_ws, size_t ws_size,
                              hipStream_t stream)
{
    const int*   edges = (const int*)  d_in[0];
    const float* ent   = (const float*)d_in[1];
    const float* relE  = (const float*)d_in[2];
    const float* Wm1   = (const float*)d_in[3];
    const float* Wl1   = (const float*)d_in[4];
    const float* Wm2   = (const float*)d_in[5];
    const float* Wl2   = (const float*)d_in[6];
    const float* Wtg   = (const float*)d_in[7];
    const float* bias  = (const float*)d_in[8];
    float* Dout = (float*)d_out;

    const size_t NM2 = (size_t)NNODES * RSTRIDE;

    __bf16* hR   = (__bf16*)d_ws;                      // h rows (stride 224)
    __bf16* SR   = hR + NM2;                           // S1/S2 rows
    __bf16* BR   = SR + NM2;                           // layer-1 out rows
    __bf16* RnR  = BR + NM2;                           // normalized relation rows
    __bf16* Wpk  = RnR + (size_t)NREL * RSTRIDE;       // 5 packed weights
    __bf16* pWm1 = Wpk + 0 * (size_t)WPK_ELEMS;
    __bf16* pWl1 = Wpk + 1 * (size_t)WPK_ELEMS;
    __bf16* pWm2 = Wpk + 2 * (size_t)WPK_ELEMS;
    __bf16* pWl2 = Wpk + 3 * (size_t)WPK_ELEMS;
    __bf16* pWtg = Wpk + 4 * (size_t)WPK_ELEMS;
    // batched CSR arrays over 3N super-nodes
    int*  counts = (int*)(Wpk + 5 * (size_t)WPK_ELEMS);
    int*  cursor = counts + TSTEPS * NNODES;
    int2* sorted = (int2*)(cursor + TSTEPS * NNODES);
    int*  offs   = (int*)(sorted + TSTEPS * NEDGES);
    int*  bsum   = offs + (TSTEPS * NNODES + 1);
    int*  stmp   = bsum + SCAN_B;

    dim3 blk(256);
    const int GD = (NNODES + 63) / 64;      // 1563 (dual, BM=64, 512 thr)
    const int GM = (NNODES + 31) / 32;      // 3125 (mega, BM=32, 512 thr)
    dim3 ngrid32((NNODES * 32 + 255) / 256);
    dim3 rgrid32((NREL * 32 + 255) / 256);
    dim3 agrid((NNODES + 3) / 4);
    dim3 egrid3((TSTEPS * NEDGES + 255) / 256);
    const int NTOT = TSTEPS * NNODES;               // 300000
    const int NSB  = (NTOT + SCAN_B - 1) / SCAN_B;  // 293

    // ---- weights + prologue norms ----
    pack_w<<<dim3((5 * KSTEPS * NB16 * 64 + 255) / 256), blk, 0, stream>>>(Wm1, Wl1, Wm2, Wl2, Wtg, Wpk);
    l2norm_pro<<<ngrid32, blk, 0, stream>>>(ent, hR, NNODES);
    l2norm_pro<<<rgrid32, blk, 0, stream>>>(relE, RnR, NREL);

    // ---- batched CSR build (all timesteps) ----
    hipMemsetAsync(counts, 0, 2 * NTOT * sizeof(int), stream);   // counts + cursor
    edge_hist3<<<egrid3, blk, 0, stream>>>(edges, counts);
    scan1<<<NSB, SCAN_B, 0, stream>>>(counts, stmp, bsum, NTOT);
    scan2<<<1, SCAN_B, 0, stream>>>(bsum, NSB);
    scan3<<<NSB, SCAN_B, 0, stream>>>(stmp, bsum, offs, NTOT);
    edge_fill3<<<egrid3, blk, 0, stream>>>(edges, offs, cursor, sorted);

    for (int t = 0; t < 3; ++t) {
        const int* offsT = offs + (size_t)t * NNODES;
        // ---- layer 1: aggregate in h-space, then dual-stream GEMM ----
        agg_S<<<agrid, blk, 0, stream>>>(offsT, sorted, hR, RnR, SR, NNODES);
        gemm_dual<<<GD, dim3(512), 0, stream>>>(SR, pWm1, hR, pWl1, BR, NNODES);
        // ---- layer 2 + gate + blend + norms (mega; HR in-place) ----
        agg_S<<<agrid, blk, 0, stream>>>(offsT, sorted, BR, RnR, SR, NNODES);
        gemm_mega<<<GM, dim3(512), 0, stream>>>(SR, pWm2, BR, pWl2, hR, pWtg, bias,
                                                Dout, NNODES, (t == 2) ? 1 : 0);
    }
}

// Round 12
// 936.139 us; speedup vs baseline: 1.7440x; 1.1427x over previous
//
#include <hip/hip_runtime.h>
#include <math.h>

#define DIMN    200
#define RSTRIDE 224          // padded row stride: 448B = 7 x 64B lines
#define NNODES  100000
#define NREL    500
#define NEDGES  200000
#define TSTEPS  3
#define KSTEPS  7            // K padded 200 -> 224 = 7*32
#define NB16    16           // N padded 200 -> 256
#define WPK_ELEMS (KSTEPS * NB16 * 64 * 8)   // 57344 bf16 per weight
#define SCAN_B  1024

typedef float  v4f  __attribute__((ext_vector_type(4)));
typedef __bf16 v8bf __attribute__((ext_vector_type(8)));

// R12 (= R11 intent, compile-fixed): global_load_lds offset arg must be a
// literal constant -> per-step displacement moved into the source POINTER
// (runtime value allowed); offset stays 0.
#define GLOAD_LDS16(src, dst) \
    __builtin_amdgcn_global_load_lds((const __attribute__((address_space(1))) void*)(src), \
                                     (__attribute__((address_space(3))) void*)(dst), 16, 0, 0)

// ---------------- prologue l2norm: fp32 rows -> bf16 stride-224 rows (zero pad) ----------------
__launch_bounds__(256)
__global__ void l2norm_pro(const float* __restrict__ in, __bf16* __restrict__ out, int nrows)
{
    int idx  = blockIdx.x * 256 + threadIdx.x;
    int node = idx >> 5;
    int ch   = idx & 31;
    if (node >= nrows) return;
    float v[8] = {};
    if (ch < 25) {
        const float4* p = (const float4*)(in + (size_t)node * DIMN + ch * 8);
        float4 f0 = p[0], f1 = p[1];
        v[0]=f0.x; v[1]=f0.y; v[2]=f0.z; v[3]=f0.w;
        v[4]=f1.x; v[5]=f1.y; v[6]=f1.z; v[7]=f1.w;
    }
    float ss = 0.0f;
    #pragma unroll
    for (int k = 0; k < 8; ++k) ss += v[k] * v[k];
    #pragma unroll
    for (int off = 16; off; off >>= 1) ss += __shfl_xor(ss, off, 64);
    float s = 1.0f / fmaxf(sqrtf(ss), 1e-12f);
    if (ch < 28) {
        v8bf o;
        #pragma unroll
        for (int k = 0; k < 8; ++k) o[k] = (ch < 25) ? (__bf16)(v[k] * s) : (__bf16)0.0f;
        *(v8bf*)(out + (size_t)node * RSTRIDE + ch * 8) = o;
    }
}

// ---------------- batched CSR build over (t,node) super-nodes (R6 proven) ----------------
__launch_bounds__(256)
__global__ void edge_hist3(const int* __restrict__ edges, int* __restrict__ counts)
{
    int e = blockIdx.x * 256 + threadIdx.x;
    if (e < TSTEPS * NEDGES) {
        int t = e / NEDGES;
        atomicAdd(&counts[t * NNODES + edges[(size_t)e * 3 + 2]], 1);
    }
}

__launch_bounds__(SCAN_B)
__global__ void scan1(const int* __restrict__ counts, int* __restrict__ tmp,
                      int* __restrict__ bsum, int n)
{
    __shared__ int sh[SCAN_B];
    int i = blockIdx.x * SCAN_B + threadIdx.x;
    int v = (i < n) ? counts[i] : 0;
    sh[threadIdx.x] = v;
    __syncthreads();
    for (int off = 1; off < SCAN_B; off <<= 1) {
        int t = (threadIdx.x >= off) ? sh[threadIdx.x - off] : 0;
        __syncthreads();
        sh[threadIdx.x] += t;
        __syncthreads();
    }
    if (i < n) tmp[i] = sh[threadIdx.x];
    if (threadIdx.x == SCAN_B - 1) bsum[blockIdx.x] = sh[threadIdx.x];
}

__launch_bounds__(SCAN_B)
__global__ void scan2(int* __restrict__ bsum, int nb)
{
    __shared__ int sh[SCAN_B];
    int v = (threadIdx.x < nb) ? bsum[threadIdx.x] : 0;
    sh[threadIdx.x] = v;
    __syncthreads();
    for (int off = 1; off < SCAN_B; off <<= 1) {
        int t = (threadIdx.x >= off) ? sh[threadIdx.x - off] : 0;
        __syncthreads();
        sh[threadIdx.x] += t;
        __syncthreads();
    }
    if (threadIdx.x < nb) bsum[threadIdx.x] = sh[threadIdx.x] - v;
}

__launch_bounds__(SCAN_B)
__global__ void scan3(const int* __restrict__ tmp, const int* __restrict__ bsum,
                      int* __restrict__ offs, int n)
{
    int i = blockIdx.x * SCAN_B + threadIdx.x;
    if (i < n) offs[i + 1] = tmp[i] + bsum[blockIdx.x];
    if (i == 0) offs[0] = 0;
}

__launch_bounds__(256)
__global__ void edge_fill3(const int* __restrict__ edges, const int* __restrict__ offs,
                           int* __restrict__ cursor, int2* __restrict__ sorted)
{
    int e = blockIdx.x * 256 + threadIdx.x;
    if (e >= TSTEPS * NEDGES) return;
    int t = e / NEDGES;
    int s = edges[(size_t)e * 3 + 0];
    int r = edges[(size_t)e * 3 + 1];
    int d = edges[(size_t)e * 3 + 2];
    int sn = t * NNODES + d;
    int p = offs[sn] + atomicAdd(&cursor[sn], 1);
    sorted[p] = make_int2(s, r);
}

// ---------------- aggregate: S = segsum(x[src] + r[rel]) / max(deg,1) -> stride-224 rows ----------------
__launch_bounds__(256)
__global__ void agg_S(const int* __restrict__ offs, const int2* __restrict__ sorted,
                      const __bf16* __restrict__ XR, const __bf16* __restrict__ RnR,
                      __bf16* __restrict__ SR, int nnodes)
{
    int wave = (int)((blockIdx.x * blockDim.x + threadIdx.x) >> 6);
    int lane = threadIdx.x & 63;
    if (wave >= nnodes) return;
    int beg = offs[wave], end = offs[wave + 1];
    int ch = lane & 31;
    bool act = ch < 25;

    float acc[8] = {};
    for (int e = beg; e < end; ++e) {
        int2 sr = sorted[e];
        const __bf16* base = (lane < 32) ? (XR + (size_t)sr.x * RSTRIDE)
                                         : (RnR + (size_t)sr.y * RSTRIDE);
        v8bf v = {};
        if (act) v = *(const v8bf*)(base + ch * 8);
        #pragma unroll
        for (int k = 0; k < 8; ++k) acc[k] += (float)v[k];
    }
    #pragma unroll
    for (int k = 0; k < 8; ++k) acc[k] += __shfl_xor(acc[k], 32, 64);

    float rdeg = 1.0f / fmaxf((float)(end - beg), 1.0f);
    if (lane < 32 && ch < 28) {
        v8bf o;
        #pragma unroll
        for (int k = 0; k < 8; ++k) o[k] = act ? (__bf16)(acc[k] * rdeg) : (__bf16)0.0f;
        *(v8bf*)(SR + (size_t)wave * RSTRIDE + ch * 8) = o;
    }
}

// ---------------- weight pack (R6 coalesced): chunk c = s*1024 + nb*64 + lane ----------------
__launch_bounds__(256)
__global__ void pack_w(const float* __restrict__ W0, const float* __restrict__ W1,
                       const float* __restrict__ W2, const float* __restrict__ W3,
                       const float* __restrict__ W4, __bf16* __restrict__ out)
{
    int id = blockIdx.x * 256 + threadIdx.x;
    const int nchunk = KSTEPS * NB16 * 64;        // 7168
    if (id >= 5 * nchunk) return;
    int wi = id / nchunk;
    int c  = id % nchunk;
    const float* W = wi == 0 ? W0 : wi == 1 ? W1 : wi == 2 ? W2 : wi == 3 ? W3 : W4;
    int s    = c >> 10;
    int nb   = (c & 1023) >> 6;
    int lane = c & 63;
    int kbase = s * 32 + (lane >> 4) * 8;
    int n     = nb * 16 + (lane & 15);
    __bf16* dst = out + (size_t)wi * WPK_ELEMS + (size_t)c * 8;
    #pragma unroll
    for (int j = 0; j < 8; ++j) {
        int k = kbase + j;
        float v = (k < DIMN && n < DIMN) ? W[k * DIMN + n] : 0.0f;
        dst[j] = (__bf16)v;
    }
}

// ---------------- G1: Out = A1@W1 + A2@W2 ; BM=64, 8 waves x ni=2, row-major A (R10 form) ----------------
__launch_bounds__(512)
__global__ void gemm_dual(const __bf16* __restrict__ A1, const __bf16* __restrict__ W1,
                          const __bf16* __restrict__ A2, const __bf16* __restrict__ W2,
                          __bf16* __restrict__ OutR, int M)
{
    const int tid  = threadIdx.x;
    const int w    = tid >> 6;          // 0..7
    const int lane = tid & 63;
    const int rlo  = lane & 15;
    const int g8   = lane >> 4;
    const int bm   = blockIdx.x * 64;

    __shared__ __bf16 T[64][264];

    v4f acc[4][2];
    #pragma unroll
    for (int mi = 0; mi < 4; ++mi)
        #pragma unroll
        for (int ni = 0; ni < 2; ++ni)
            acc[mi][ni] = (v4f){0.f, 0.f, 0.f, 0.f};

    const __bf16* a1p[4];
    const __bf16* a2p[4];
    #pragma unroll
    for (int mi = 0; mi < 4; ++mi) {
        int rr = bm + mi * 16 + rlo;
        if (rr >= M) rr = M - 1;                // clamp: outputs masked on emit
        a1p[mi] = A1 + (size_t)rr * RSTRIDE + g8 * 8;
        a2p[mi] = A2 + (size_t)rr * RSTRIDE + g8 * 8;
    }
    // coalesced B: wave w covers col blocks w*2+ni; lane-consecutive 16B
    const __bf16* w1b = W1 + (size_t)(w * 2 * 64 + lane) * 8;
    const __bf16* w2b = W2 + (size_t)(w * 2 * 64 + lane) * 8;

    #pragma unroll
    for (int s = 0; s < KSTEPS; ++s) {
        v8bf b1[2], b2[2];
        #pragma unroll
        for (int ni = 0; ni < 2; ++ni) {
            size_t bo = ((size_t)s * NB16 * 64 + ni * 64) * 8;
            b1[ni] = *(const v8bf*)(w1b + bo);
            b2[ni] = *(const v8bf*)(w2b + bo);
        }
        #pragma unroll
        for (int mi = 0; mi < 4; ++mi) {
            v8bf a1 = *(const v8bf*)(a1p[mi] + s * 32);
            v8bf a2 = *(const v8bf*)(a2p[mi] + s * 32);
            #pragma unroll
            for (int ni = 0; ni < 2; ++ni)
                acc[mi][ni] = __builtin_amdgcn_mfma_f32_16x16x32_bf16(a1, b1[ni], acc[mi][ni], 0, 0, 0);
            #pragma unroll
            for (int ni = 0; ni < 2; ++ni)
                acc[mi][ni] = __builtin_amdgcn_mfma_f32_16x16x32_bf16(a2, b2[ni], acc[mi][ni], 0, 0, 0);
        }
    }

    // D -> LDS tile (row = mi*16 + g8*4 + reg, col = w*32 + ni*16 + rlo)
    #pragma unroll
    for (int mi = 0; mi < 4; ++mi)
        #pragma unroll
        for (int reg = 0; reg < 4; ++reg)
            #pragma unroll
            for (int ni = 0; ni < 2; ++ni)
                T[mi * 16 + g8 * 4 + reg][w * 32 + ni * 16 + rlo] = (__bf16)acc[mi][ni][reg];
    __syncthreads();

    // row emit: 64 rows * 28 chunks = 1792 (cols 200-223 are zero via weight pad)
    #pragma unroll
    for (int j = 0; j < 4; ++j) {
        int it = tid + j * 512;
        if (it < 1792) {
            int row = it / 28, ch = it - row * 28;
            int gr = bm + row;
            if (gr < M)
                *(v8bf*)(OutR + (size_t)gr * RSTRIDE + ch * 8) = *(const v8bf*)&T[row][ch * 8];
        }
    }
}

// ---------------- G2 mega: cur = l2norm(A1@W1 + A2@W2); gate = sigmoid(A3@W3 + bias);
//                  h' = l2norm(gate*cur + (1-gate)*h); A3 = HR (own rows, in-place safe)
// R12: A staged via global_load_lds (per-lane gather src -> linear LDS frag), dbuf.
// GM*32 == NNODES exactly, so no row clamp needed in mega.
__launch_bounds__(512)
__global__ void gemm_mega(const __bf16* __restrict__ A1, const __bf16* __restrict__ W1,
                          const __bf16* __restrict__ A2, const __bf16* __restrict__ W2,
                          __bf16* __restrict__ HR, const __bf16* __restrict__ W3,
                          const float* __restrict__ Bias,
                          float* __restrict__ DoutF, int M, int finalStep)
{
    const int tid  = threadIdx.x;
    const int w    = tid >> 6;          // 0..7
    const int lane = tid & 63;
    const int rlo  = lane & 15;
    const int g8   = lane >> 4;
    const int bm   = blockIdx.x * 32;

    __shared__ __bf16 As[2][6][512];    // 12KB: chunk c = stream*2 + nb, dbuf
    __shared__ __bf16 T[32][264];
    __shared__ float  rsq1[32][8];
    __shared__ float  rsq2[32][8];

    v4f acc1[2][2], acc2[2][2];
    #pragma unroll
    for (int mi = 0; mi < 2; ++mi)
        #pragma unroll
        for (int ni = 0; ni < 2; ++ni) {
            acc1[mi][ni] = (v4f){0.f, 0.f, 0.f, 0.f};
            acc2[mi][ni] = (v4f){0.f, 0.f, 0.f, 0.f};
        }

    // staging source for issuing waves (w<6): stream = w>>1 in {A1,A2,HR}, nb = w&1
    // per-lane src: row = bm + nb*16 + (lane&15), col base = (lane>>4)*8; +s*32 elems per step
    const __bf16* sb   = (w >> 1) == 0 ? A1 : ((w >> 1) == 1 ? A2 : HR);
    const __bf16* asrc = sb + (size_t)(bm + (w & 1) * 16 + rlo) * RSTRIDE + g8 * 8;

    const __bf16* w1b = W1 + (size_t)(w * 2 * 64 + lane) * 8;
    const __bf16* w2b = W2 + (size_t)(w * 2 * 64 + lane) * 8;
    const __bf16* w3b = W3 + (size_t)(w * 2 * 64 + lane) * 8;

    // prologue: stage s=0 into buffer 0
    if (w < 6)
        GLOAD_LDS16(asrc, &As[0][w][0]);
    __syncthreads();    // drains issuer vmcnt; buffer 0 visible

    #pragma unroll
    for (int s = 0; s < KSTEPS; ++s) {
        // prefetch next step into the other buffer (async, drained at end-of-iter barrier)
        if (s < KSTEPS - 1 && w < 6)
            GLOAD_LDS16(asrc + (s + 1) * 32, &As[(s + 1) & 1][w][0]);

        v8bf b1[2], b2[2], b3[2];
        #pragma unroll
        for (int ni = 0; ni < 2; ++ni) {
            size_t bo = ((size_t)s * NB16 * 64 + ni * 64) * 8;
            b1[ni] = *(const v8bf*)(w1b + bo);
            b2[ni] = *(const v8bf*)(w2b + bo);
            b3[ni] = *(const v8bf*)(w3b + bo);
        }
        #pragma unroll
        for (int mi = 0; mi < 2; ++mi) {
            v8bf a1 = *(const v8bf*)&As[s & 1][0 * 2 + mi][lane * 8];
            v8bf a2 = *(const v8bf*)&As[s & 1][1 * 2 + mi][lane * 8];
            v8bf a3 = *(const v8bf*)&As[s & 1][2 * 2 + mi][lane * 8];
            #pragma unroll
            for (int ni = 0; ni < 2; ++ni)
                acc1[mi][ni] = __builtin_amdgcn_mfma_f32_16x16x32_bf16(a1, b1[ni], acc1[mi][ni], 0, 0, 0);
            #pragma unroll
            for (int ni = 0; ni < 2; ++ni)
                acc1[mi][ni] = __builtin_amdgcn_mfma_f32_16x16x32_bf16(a2, b2[ni], acc1[mi][ni], 0, 0, 0);
            #pragma unroll
            for (int ni = 0; ni < 2; ++ni)
                acc2[mi][ni] = __builtin_amdgcn_mfma_f32_16x16x32_bf16(a3, b3[ni], acc2[mi][ni], 0, 0, 0);
        }
        __syncthreads();   // publish next buffer; all reads of current buffer done
    }

    // cur row sums-of-squares (cols >= 200 are zero via weight padding)
    #pragma unroll
    for (int mi = 0; mi < 2; ++mi)
        #pragma unroll
        for (int reg = 0; reg < 4; ++reg) {
            float ss = 0.0f;
            #pragma unroll
            for (int ni = 0; ni < 2; ++ni) ss += acc1[mi][ni][reg] * acc1[mi][ni][reg];
            ss += __shfl_xor(ss, 1, 64);
            ss += __shfl_xor(ss, 2, 64);
            ss += __shfl_xor(ss, 4, 64);
            ss += __shfl_xor(ss, 8, 64);
            if (rlo == 0) rsq1[mi * 16 + g8 * 4 + reg][w] = ss;
        }
    // stage h rows into T (overwritten only after blend completes)
    #pragma unroll
    for (int j = 0; j < 2; ++j) {
        int it = tid + j * 512;
        if (it < 800) {
            int row = it / 25, ch = it - row * 25;
            int gr = bm + row;
            v8bf hv = {};
            if (gr < M) hv = *(const v8bf*)(HR + (size_t)gr * RSTRIDE + ch * 8);
            *(v8bf*)&T[row][ch * 8] = hv;
        }
    }
    __syncthreads();

    // blend: v = gate*cur + (1-gate)*h  (store into acc1), second row reduce
    #pragma unroll
    for (int mi = 0; mi < 2; ++mi)
        #pragma unroll
        for (int reg = 0; reg < 4; ++reg) {
            int rl = mi * 16 + g8 * 4 + reg;
            float tot = rsq1[rl][0] + rsq1[rl][1] + rsq1[rl][2] + rsq1[rl][3]
                      + rsq1[rl][4] + rsq1[rl][5] + rsq1[rl][6] + rsq1[rl][7];
            float sc1 = 1.0f / fmaxf(sqrtf(tot), 1e-12f);
            float ss = 0.0f;
            #pragma unroll
            for (int ni = 0; ni < 2; ++ni) {
                int c = w * 32 + ni * 16 + rlo;
                float v = 0.0f;
                if (c < DIMN) {
                    float cur = acc1[mi][ni][reg] * sc1;
                    float gg  = 1.0f / (1.0f + __expf(-(acc2[mi][ni][reg] + Bias[c])));
                    float hh  = (float)T[rl][c];
                    v = gg * cur + (1.0f - gg) * hh;
                }
                acc1[mi][ni][reg] = v;
                ss += v * v;
            }
            ss += __shfl_xor(ss, 1, 64);
            ss += __shfl_xor(ss, 2, 64);
            ss += __shfl_xor(ss, 4, 64);
            ss += __shfl_xor(ss, 8, 64);
            if (rlo == 0) rsq2[rl][w] = ss;
        }
    __syncthreads();

    // final scale -> T (overwrites staged h; all h reads completed before barrier above)
    #pragma unroll
    for (int mi = 0; mi < 2; ++mi)
        #pragma unroll
        for (int reg = 0; reg < 4; ++reg) {
            int rl = mi * 16 + g8 * 4 + reg;
            float tot = rsq2[rl][0] + rsq2[rl][1] + rsq2[rl][2] + rsq2[rl][3]
                      + rsq2[rl][4] + rsq2[rl][5] + rsq2[rl][6] + rsq2[rl][7];
            float sc2 = 1.0f / fmaxf(sqrtf(tot), 1e-12f);
            #pragma unroll
            for (int ni = 0; ni < 2; ++ni) {
                int c = w * 32 + ni * 16 + rlo;
                T[rl][c] = (__bf16)(acc1[mi][ni][reg] * sc2);
            }
        }
    __syncthreads();

    if (!finalStep) {
        // h' rows: 32 rows * 28 chunks = 896 (cols 200-223 zero)
        #pragma unroll
        for (int j = 0; j < 2; ++j) {
            int it = tid + j * 512;
            if (it < 896) {
                int row = it / 28, ch = it - row * 28;
                int gr = bm + row;
                if (gr < M)
                    *(v8bf*)(HR + (size_t)gr * RSTRIDE + ch * 8) = *(const v8bf*)&T[row][ch * 8];
            }
        }
    } else {
        // fp32 output rows (stride DIMN)
        #pragma unroll
        for (int j = 0; j < 2; ++j) {
            int it = tid + j * 512;
            if (it < 800) {
                int row = it / 25, ch = it - row * 25;
                int gr = bm + row;
                if (gr < M) {
                    v8bf o = *(const v8bf*)&T[row][ch * 8];
                    float4* q0 = (float4*)(DoutF + (size_t)gr * DIMN + ch * 8);
                    q0[0] = make_float4((float)o[0], (float)o[1], (float)o[2], (float)o[3]);
                    q0[1] = make_float4((float)o[4], (float)o[5], (float)o[6], (float)o[7]);
                }
            }
        }
    }
}

extern "C" void kernel_launch(void* const* d_in, const int* in_sizes, int n_in,
                              void* d_out, int out_size, void* d_ws, size_t ws_size,
                              hipStream_t stream)
{
    const int*   edges = (const int*)  d_in[0];
    const float* ent   = (const float*)d_in[1];
    const float* relE  = (const float*)d_in[2];
    const float* Wm1   = (const float*)d_in[3];
    const float* Wl1   = (const float*)d_in[4];
    const float* Wm2   = (const float*)d_in[5];
    const float* Wl2   = (const float*)d_in[6];
    const float* Wtg   = (const float*)d_in[7];
    const float* bias  = (const float*)d_in[8];
    float* Dout = (float*)d_out;

    const size_t NM2 = (size_t)NNODES * RSTRIDE;

    __bf16* hR   = (__bf16*)d_ws;                      // h rows (stride 224)
    __bf16* SR   = hR + NM2;                           // S1/S2 rows
    __bf16* BR   = SR + NM2;                           // layer-1 out rows
    __bf16* RnR  = BR + NM2;                           // normalized relation rows
    __bf16* Wpk  = RnR + (size_t)NREL * RSTRIDE;       // 5 packed weights
    __bf16* pWm1 = Wpk + 0 * (size_t)WPK_ELEMS;
    __bf16* pWl1 = Wpk + 1 * (size_t)WPK_ELEMS;
    __bf16* pWm2 = Wpk + 2 * (size_t)WPK_ELEMS;
    __bf16* pWl2 = Wpk + 3 * (size_t)WPK_ELEMS;
    __bf16* pWtg = Wpk + 4 * (size_t)WPK_ELEMS;
    // batched CSR arrays over 3N super-nodes
    int*  counts = (int*)(Wpk + 5 * (size_t)WPK_ELEMS);
    int*  cursor = counts + TSTEPS * NNODES;
    int2* sorted = (int2*)(cursor + TSTEPS * NNODES);
    int*  offs   = (int*)(sorted + TSTEPS * NEDGES);
    int*  bsum   = offs + (TSTEPS * NNODES + 1);
    int*  stmp   = bsum + SCAN_B;

    dim3 blk(256);
    const int GD = (NNODES + 63) / 64;      // 1563 (dual, BM=64, 512 thr)
    const int GM = (NNODES + 31) / 32;      // 3125 (mega, BM=32, 512 thr)
    dim3 ngrid32((NNODES * 32 + 255) / 256);
    dim3 rgrid32((NREL * 32 + 255) / 256);
    dim3 agrid((NNODES + 3) / 4);
    dim3 egrid3((TSTEPS * NEDGES + 255) / 256);
    const int NTOT = TSTEPS * NNODES;               // 300000
    const int NSB  = (NTOT + SCAN_B - 1) / SCAN_B;  // 293

    // ---- weights + prologue norms ----
    pack_w<<<dim3((5 * KSTEPS * NB16 * 64 + 255) / 256), blk, 0, stream>>>(Wm1, Wl1, Wm2, Wl2, Wtg, Wpk);
    l2norm_pro<<<ngrid32, blk, 0, stream>>>(ent, hR, NNODES);
    l2norm_pro<<<rgrid32, blk, 0, stream>>>(relE, RnR, NREL);

    // ---- batched CSR build (all timesteps) ----
    hipMemsetAsync(counts, 0, 2 * NTOT * sizeof(int), stream);   // counts + cursor
    edge_hist3<<<egrid3, blk, 0, stream>>>(edges, counts);
    scan1<<<NSB, SCAN_B, 0, stream>>>(counts, stmp, bsum, NTOT);
    scan2<<<1, SCAN_B, 0, stream>>>(bsum, NSB);
    scan3<<<NSB, SCAN_B, 0, stream>>>(stmp, bsum, offs, NTOT);
    edge_fill3<<<egrid3, blk, 0, stream>>>(edges, offs, cursor, sorted);

    for (int t = 0; t < 3; ++t) {
        const int* offsT = offs + (size_t)t * NNODES;
        // ---- layer 1: aggregate in h-space, then dual-stream GEMM ----
        agg_S<<<agrid, blk, 0, stream>>>(offsT, sorted, hR, RnR, SR, NNODES);
        gemm_dual<<<GD, dim3(512), 0, stream>>>(SR, pWm1, hR, pWl1, BR, NNODES);
        // ---- layer 2 + gate + blend + norms (mega; HR in-place) ----
        agg_S<<<agrid, blk, 0, stream>>>(offsT, sorted, BR, RnR, SR, NNODES);
        gemm_mega<<<GM, dim3(512), 0, stream>>>(SR, pWm2, BR, pWl2, hR, pWtg, bias,
                                                Dout, NNODES, (t == 2) ? 1 : 0);
    }
}

// Round 13
// 857.972 us; speedup vs baseline: 1.9028x; 1.0911x over previous
//
#include <hip/hip_runtime.h>
#include <math.h>

#define DIMN    200
#define RSTRIDE 224          // padded row stride: 448B = 7 x 64B lines
#define NNODES  100000
#define NREL    500
#define NEDGES  200000
#define TSTEPS  3
#define KSTEPS  7            // K padded 200 -> 224 = 7*32
#define NB16    16           // N padded 200 -> 256
#define WPK_ELEMS (KSTEPS * NB16 * 64 * 8)   // 57344 bf16 per weight
#define SCAN_B  1024

typedef float  v4f  __attribute__((ext_vector_type(4)));
typedef __bf16 v8bf __attribute__((ext_vector_type(8)));

// R13: R12's DMA-gather A-staging (global_load_lds, per-lane src = row-major
// gather, linear LDS dest in MFMA fragment order) ported to gemm_dual.
// dual: 8 chunks/K-step (2 streams x 4 row-blocks) = 1 per wave; staging
// buffer aliased onto T (disjoint lifetimes, existing barriers order reuse).
#define GLOAD_LDS16(src, dst) \
    __builtin_amdgcn_global_load_lds((const __attribute__((address_space(1))) void*)(src), \
                                     (__attribute__((address_space(3))) void*)(dst), 16, 0, 0)

// ---------------- prologue l2norm: fp32 rows -> bf16 stride-224 rows (zero pad) ----------------
__launch_bounds__(256)
__global__ void l2norm_pro(const float* __restrict__ in, __bf16* __restrict__ out, int nrows)
{
    int idx  = blockIdx.x * 256 + threadIdx.x;
    int node = idx >> 5;
    int ch   = idx & 31;
    if (node >= nrows) return;
    float v[8] = {};
    if (ch < 25) {
        const float4* p = (const float4*)(in + (size_t)node * DIMN + ch * 8);
        float4 f0 = p[0], f1 = p[1];
        v[0]=f0.x; v[1]=f0.y; v[2]=f0.z; v[3]=f0.w;
        v[4]=f1.x; v[5]=f1.y; v[6]=f1.z; v[7]=f1.w;
    }
    float ss = 0.0f;
    #pragma unroll
    for (int k = 0; k < 8; ++k) ss += v[k] * v[k];
    #pragma unroll
    for (int off = 16; off; off >>= 1) ss += __shfl_xor(ss, off, 64);
    float s = 1.0f / fmaxf(sqrtf(ss), 1e-12f);
    if (ch < 28) {
        v8bf o;
        #pragma unroll
        for (int k = 0; k < 8; ++k) o[k] = (ch < 25) ? (__bf16)(v[k] * s) : (__bf16)0.0f;
        *(v8bf*)(out + (size_t)node * RSTRIDE + ch * 8) = o;
    }
}

// ---------------- batched CSR build over (t,node) super-nodes (R6 proven) ----------------
__launch_bounds__(256)
__global__ void edge_hist3(const int* __restrict__ edges, int* __restrict__ counts)
{
    int e = blockIdx.x * 256 + threadIdx.x;
    if (e < TSTEPS * NEDGES) {
        int t = e / NEDGES;
        atomicAdd(&counts[t * NNODES + edges[(size_t)e * 3 + 2]], 1);
    }
}

__launch_bounds__(SCAN_B)
__global__ void scan1(const int* __restrict__ counts, int* __restrict__ tmp,
                      int* __restrict__ bsum, int n)
{
    __shared__ int sh[SCAN_B];
    int i = blockIdx.x * SCAN_B + threadIdx.x;
    int v = (i < n) ? counts[i] : 0;
    sh[threadIdx.x] = v;
    __syncthreads();
    for (int off = 1; off < SCAN_B; off <<= 1) {
        int t = (threadIdx.x >= off) ? sh[threadIdx.x - off] : 0;
        __syncthreads();
        sh[threadIdx.x] += t;
        __syncthreads();
    }
    if (i < n) tmp[i] = sh[threadIdx.x];
    if (threadIdx.x == SCAN_B - 1) bsum[blockIdx.x] = sh[threadIdx.x];
}

__launch_bounds__(SCAN_B)
__global__ void scan2(int* __restrict__ bsum, int nb)
{
    __shared__ int sh[SCAN_B];
    int v = (threadIdx.x < nb) ? bsum[threadIdx.x] : 0;
    sh[threadIdx.x] = v;
    __syncthreads();
    for (int off = 1; off < SCAN_B; off <<= 1) {
        int t = (threadIdx.x >= off) ? sh[threadIdx.x - off] : 0;
        __syncthreads();
        sh[threadIdx.x] += t;
        __syncthreads();
    }
    if (threadIdx.x < nb) bsum[threadIdx.x] = sh[threadIdx.x] - v;
}

__launch_bounds__(SCAN_B)
__global__ void scan3(const int* __restrict__ tmp, const int* __restrict__ bsum,
                      int* __restrict__ offs, int n)
{
    int i = blockIdx.x * SCAN_B + threadIdx.x;
    if (i < n) offs[i + 1] = tmp[i] + bsum[blockIdx.x];
    if (i == 0) offs[0] = 0;
}

__launch_bounds__(256)
__global__ void edge_fill3(const int* __restrict__ edges, const int* __restrict__ offs,
                           int* __restrict__ cursor, int2* __restrict__ sorted)
{
    int e = blockIdx.x * 256 + threadIdx.x;
    if (e >= TSTEPS * NEDGES) return;
    int t = e / NEDGES;
    int s = edges[(size_t)e * 3 + 0];
    int r = edges[(size_t)e * 3 + 1];
    int d = edges[(size_t)e * 3 + 2];
    int sn = t * NNODES + d;
    int p = offs[sn] + atomicAdd(&cursor[sn], 1);
    sorted[p] = make_int2(s, r);
}

// ---------------- aggregate: S = segsum(x[src] + r[rel]) / max(deg,1) -> stride-224 rows ----------------
__launch_bounds__(256)
__global__ void agg_S(const int* __restrict__ offs, const int2* __restrict__ sorted,
                      const __bf16* __restrict__ XR, const __bf16* __restrict__ RnR,
                      __bf16* __restrict__ SR, int nnodes)
{
    int wave = (int)((blockIdx.x * blockDim.x + threadIdx.x) >> 6);
    int lane = threadIdx.x & 63;
    if (wave >= nnodes) return;
    int beg = offs[wave], end = offs[wave + 1];
    int ch = lane & 31;
    bool act = ch < 25;

    float acc[8] = {};
    for (int e = beg; e < end; ++e) {
        int2 sr = sorted[e];
        const __bf16* base = (lane < 32) ? (XR + (size_t)sr.x * RSTRIDE)
                                         : (RnR + (size_t)sr.y * RSTRIDE);
        v8bf v = {};
        if (act) v = *(const v8bf*)(base + ch * 8);
        #pragma unroll
        for (int k = 0; k < 8; ++k) acc[k] += (float)v[k];
    }
    #pragma unroll
    for (int k = 0; k < 8; ++k) acc[k] += __shfl_xor(acc[k], 32, 64);

    float rdeg = 1.0f / fmaxf((float)(end - beg), 1.0f);
    if (lane < 32 && ch < 28) {
        v8bf o;
        #pragma unroll
        for (int k = 0; k < 8; ++k) o[k] = act ? (__bf16)(acc[k] * rdeg) : (__bf16)0.0f;
        *(v8bf*)(SR + (size_t)wave * RSTRIDE + ch * 8) = o;
    }
}

// ---------------- weight pack (R6 coalesced): chunk c = s*1024 + nb*64 + lane ----------------
__launch_bounds__(256)
__global__ void pack_w(const float* __restrict__ W0, const float* __restrict__ W1,
                       const float* __restrict__ W2, const float* __restrict__ W3,
                       const float* __restrict__ W4, __bf16* __restrict__ out)
{
    int id = blockIdx.x * 256 + threadIdx.x;
    const int nchunk = KSTEPS * NB16 * 64;        // 7168
    if (id >= 5 * nchunk) return;
    int wi = id / nchunk;
    int c  = id % nchunk;
    const float* W = wi == 0 ? W0 : wi == 1 ? W1 : wi == 2 ? W2 : wi == 3 ? W3 : W4;
    int s    = c >> 10;
    int nb   = (c & 1023) >> 6;
    int lane = c & 63;
    int kbase = s * 32 + (lane >> 4) * 8;
    int n     = nb * 16 + (lane & 15);
    __bf16* dst = out + (size_t)wi * WPK_ELEMS + (size_t)c * 8;
    #pragma unroll
    for (int j = 0; j < 8; ++j) {
        int k = kbase + j;
        float v = (k < DIMN && n < DIMN) ? W[k * DIMN + n] : 0.0f;
        dst[j] = (__bf16)v;
    }
}

// ---------------- G1: Out = A1@W1 + A2@W2 ; BM=64, 8 waves x ni=2 ----------------
// R13: A staged via global_load_lds DMA-gather; staging buffer aliased onto T.
__launch_bounds__(512)
__global__ void gemm_dual(const __bf16* __restrict__ A1, const __bf16* __restrict__ W1,
                          const __bf16* __restrict__ A2, const __bf16* __restrict__ W2,
                          __bf16* __restrict__ OutR, int M)
{
    const int tid  = threadIdx.x;
    const int w    = tid >> 6;          // 0..7
    const int lane = tid & 63;
    const int rlo  = lane & 15;
    const int g8   = lane >> 4;
    const int bm   = blockIdx.x * 64;

    __shared__ __bf16 shm[64 * 264];                     // 33.8KB
    __bf16 (*As)[8][512] = (__bf16(*)[8][512])shm;       // [2][8][512] = 16KB alias (K-loop only)
    __bf16 (*T)[264]     = (__bf16(*)[264])shm;          // [64][264] (post-loop only)

    v4f acc[4][2];
    #pragma unroll
    for (int mi = 0; mi < 4; ++mi)
        #pragma unroll
        for (int ni = 0; ni < 2; ++ni)
            acc[mi][ni] = (v4f){0.f, 0.f, 0.f, 0.f};

    // wave w stages chunk (stream = w>>2, nb = w&3); per-lane src row = bm+nb*16+rlo
    int rr = bm + (w & 3) * 16 + rlo;
    if (rr >= M) rr = M - 1;                             // clamp: outputs masked on emit
    const __bf16* sb   = (w >> 2) == 0 ? A1 : A2;
    const __bf16* asrc = sb + (size_t)rr * RSTRIDE + g8 * 8;

    // coalesced B: wave w covers col blocks w*2+ni; lane-consecutive 16B
    const __bf16* w1b = W1 + (size_t)(w * 2 * 64 + lane) * 8;
    const __bf16* w2b = W2 + (size_t)(w * 2 * 64 + lane) * 8;

    // prologue: stage s=0 into buffer 0
    GLOAD_LDS16(asrc, &As[0][w][0]);
    __syncthreads();

    #pragma unroll
    for (int s = 0; s < KSTEPS; ++s) {
        if (s < KSTEPS - 1)
            GLOAD_LDS16(asrc + (s + 1) * 32, &As[(s + 1) & 1][w][0]);

        v8bf b1[2], b2[2];
        #pragma unroll
        for (int ni = 0; ni < 2; ++ni) {
            size_t bo = ((size_t)s * NB16 * 64 + ni * 64) * 8;
            b1[ni] = *(const v8bf*)(w1b + bo);
            b2[ni] = *(const v8bf*)(w2b + bo);
        }
        #pragma unroll
        for (int mi = 0; mi < 4; ++mi) {
            v8bf a1 = *(const v8bf*)&As[s & 1][mi][lane * 8];
            v8bf a2 = *(const v8bf*)&As[s & 1][4 + mi][lane * 8];
            #pragma unroll
            for (int ni = 0; ni < 2; ++ni)
                acc[mi][ni] = __builtin_amdgcn_mfma_f32_16x16x32_bf16(a1, b1[ni], acc[mi][ni], 0, 0, 0);
            #pragma unroll
            for (int ni = 0; ni < 2; ++ni)
                acc[mi][ni] = __builtin_amdgcn_mfma_f32_16x16x32_bf16(a2, b2[ni], acc[mi][ni], 0, 0, 0);
        }
        __syncthreads();   // publish next buffer; all reads of current done (also fences As->T reuse)
    }

    // D -> LDS tile (row = mi*16 + g8*4 + reg, col = w*32 + ni*16 + rlo); overwrites As region
    #pragma unroll
    for (int mi = 0; mi < 4; ++mi)
        #pragma unroll
        for (int reg = 0; reg < 4; ++reg)
            #pragma unroll
            for (int ni = 0; ni < 2; ++ni)
                T[mi * 16 + g8 * 4 + reg][w * 32 + ni * 16 + rlo] = (__bf16)acc[mi][ni][reg];
    __syncthreads();

    // row emit: 64 rows * 28 chunks = 1792 (cols 200-223 are zero via weight pad)
    #pragma unroll
    for (int j = 0; j < 4; ++j) {
        int it = tid + j * 512;
        if (it < 1792) {
            int row = it / 28, ch = it - row * 28;
            int gr = bm + row;
            if (gr < M)
                *(v8bf*)(OutR + (size_t)gr * RSTRIDE + ch * 8) = *(const v8bf*)&T[row][ch * 8];
        }
    }
}

// ---------------- G2 mega (R12 proven): cur = l2norm(A1@W1 + A2@W2); gate = sigmoid(A3@W3 + bias);
//                  h' = l2norm(gate*cur + (1-gate)*h); A3 = HR (own rows, in-place safe)
__launch_bounds__(512)
__global__ void gemm_mega(const __bf16* __restrict__ A1, const __bf16* __restrict__ W1,
                          const __bf16* __restrict__ A2, const __bf16* __restrict__ W2,
                          __bf16* __restrict__ HR, const __bf16* __restrict__ W3,
                          const float* __restrict__ Bias,
                          float* __restrict__ DoutF, int M, int finalStep)
{
    const int tid  = threadIdx.x;
    const int w    = tid >> 6;          // 0..7
    const int lane = tid & 63;
    const int rlo  = lane & 15;
    const int g8   = lane >> 4;
    const int bm   = blockIdx.x * 32;

    __shared__ __bf16 As[2][6][512];    // 12KB: chunk c = stream*2 + nb, dbuf
    __shared__ __bf16 T[32][264];
    __shared__ float  rsq1[32][8];
    __shared__ float  rsq2[32][8];

    v4f acc1[2][2], acc2[2][2];
    #pragma unroll
    for (int mi = 0; mi < 2; ++mi)
        #pragma unroll
        for (int ni = 0; ni < 2; ++ni) {
            acc1[mi][ni] = (v4f){0.f, 0.f, 0.f, 0.f};
            acc2[mi][ni] = (v4f){0.f, 0.f, 0.f, 0.f};
        }

    // staging source for issuing waves (w<6): stream = w>>1 in {A1,A2,HR}, nb = w&1
    const __bf16* sb   = (w >> 1) == 0 ? A1 : ((w >> 1) == 1 ? A2 : HR);
    const __bf16* asrc = sb + (size_t)(bm + (w & 1) * 16 + rlo) * RSTRIDE + g8 * 8;

    const __bf16* w1b = W1 + (size_t)(w * 2 * 64 + lane) * 8;
    const __bf16* w2b = W2 + (size_t)(w * 2 * 64 + lane) * 8;
    const __bf16* w3b = W3 + (size_t)(w * 2 * 64 + lane) * 8;

    // prologue: stage s=0 into buffer 0
    if (w < 6)
        GLOAD_LDS16(asrc, &As[0][w][0]);
    __syncthreads();    // drains issuer vmcnt; buffer 0 visible

    #pragma unroll
    for (int s = 0; s < KSTEPS; ++s) {
        if (s < KSTEPS - 1 && w < 6)
            GLOAD_LDS16(asrc + (s + 1) * 32, &As[(s + 1) & 1][w][0]);

        v8bf b1[2], b2[2], b3[2];
        #pragma unroll
        for (int ni = 0; ni < 2; ++ni) {
            size_t bo = ((size_t)s * NB16 * 64 + ni * 64) * 8;
            b1[ni] = *(const v8bf*)(w1b + bo);
            b2[ni] = *(const v8bf*)(w2b + bo);
            b3[ni] = *(const v8bf*)(w3b + bo);
        }
        #pragma unroll
        for (int mi = 0; mi < 2; ++mi) {
            v8bf a1 = *(const v8bf*)&As[s & 1][0 * 2 + mi][lane * 8];
            v8bf a2 = *(const v8bf*)&As[s & 1][1 * 2 + mi][lane * 8];
            v8bf a3 = *(const v8bf*)&As[s & 1][2 * 2 + mi][lane * 8];
            #pragma unroll
            for (int ni = 0; ni < 2; ++ni)
                acc1[mi][ni] = __builtin_amdgcn_mfma_f32_16x16x32_bf16(a1, b1[ni], acc1[mi][ni], 0, 0, 0);
            #pragma unroll
            for (int ni = 0; ni < 2; ++ni)
                acc1[mi][ni] = __builtin_amdgcn_mfma_f32_16x16x32_bf16(a2, b2[ni], acc1[mi][ni], 0, 0, 0);
            #pragma unroll
            for (int ni = 0; ni < 2; ++ni)
                acc2[mi][ni] = __builtin_amdgcn_mfma_f32_16x16x32_bf16(a3, b3[ni], acc2[mi][ni], 0, 0, 0);
        }
        __syncthreads();   // publish next buffer; all reads of current buffer done
    }

    // cur row sums-of-squares (cols >= 200 are zero via weight padding)
    #pragma unroll
    for (int mi = 0; mi < 2; ++mi)
        #pragma unroll
        for (int reg = 0; reg < 4; ++reg) {
            float ss = 0.0f;
            #pragma unroll
            for (int ni = 0; ni < 2; ++ni) ss += acc1[mi][ni][reg] * acc1[mi][ni][reg];
            ss += __shfl_xor(ss, 1, 64);
            ss += __shfl_xor(ss, 2, 64);
            ss += __shfl_xor(ss, 4, 64);
            ss += __shfl_xor(ss, 8, 64);
            if (rlo == 0) rsq1[mi * 16 + g8 * 4 + reg][w] = ss;
        }
    // stage h rows into T (overwritten only after blend completes)
    #pragma unroll
    for (int j = 0; j < 2; ++j) {
        int it = tid + j * 512;
        if (it < 800) {
            int row = it / 25, ch = it - row * 25;
            int gr = bm + row;
            v8bf hv = {};
            if (gr < M) hv = *(const v8bf*)(HR + (size_t)gr * RSTRIDE + ch * 8);
            *(v8bf*)&T[row][ch * 8] = hv;
        }
    }
    __syncthreads();

    // blend: v = gate*cur + (1-gate)*h  (store into acc1), second row reduce
    #pragma unroll
    for (int mi = 0; mi < 2; ++mi)
        #pragma unroll
        for (int reg = 0; reg < 4; ++reg) {
            int rl = mi * 16 + g8 * 4 + reg;
            float tot = rsq1[rl][0] + rsq1[rl][1] + rsq1[rl][2] + rsq1[rl][3]
                      + rsq1[rl][4] + rsq1[rl][5] + rsq1[rl][6] + rsq1[rl][7];
            float sc1 = 1.0f / fmaxf(sqrtf(tot), 1e-12f);
            float ss = 0.0f;
            #pragma unroll
            for (int ni = 0; ni < 2; ++ni) {
                int c = w * 32 + ni * 16 + rlo;
                float v = 0.0f;
                if (c < DIMN) {
                    float cur = acc1[mi][ni][reg] * sc1;
                    float gg  = 1.0f / (1.0f + __expf(-(acc2[mi][ni][reg] + Bias[c])));
                    float hh  = (float)T[rl][c];
                    v = gg * cur + (1.0f - gg) * hh;
                }
                acc1[mi][ni][reg] = v;
                ss += v * v;
            }
            ss += __shfl_xor(ss, 1, 64);
            ss += __shfl_xor(ss, 2, 64);
            ss += __shfl_xor(ss, 4, 64);
            ss += __shfl_xor(ss, 8, 64);
            if (rlo == 0) rsq2[rl][w] = ss;
        }
    __syncthreads();

    // final scale -> T (overwrites staged h; all h reads completed before barrier above)
    #pragma unroll
    for (int mi = 0; mi < 2; ++mi)
        #pragma unroll
        for (int reg = 0; reg < 4; ++reg) {
            int rl = mi * 16 + g8 * 4 + reg;
            float tot = rsq2[rl][0] + rsq2[rl][1] + rsq2[rl][2] + rsq2[rl][3]
                      + rsq2[rl][4] + rsq2[rl][5] + rsq2[rl][6] + rsq2[rl][7];
            float sc2 = 1.0f / fmaxf(sqrtf(tot), 1e-12f);
            #pragma unroll
            for (int ni = 0; ni < 2; ++ni) {
                int c = w * 32 + ni * 16 + rlo;
                T[rl][c] = (__bf16)(acc1[mi][ni][reg] * sc2);
            }
        }
    __syncthreads();

    if (!finalStep) {
        // h' rows: 32 rows * 28 chunks = 896 (cols 200-223 zero)
        #pragma unroll
        for (int j = 0; j < 2; ++j) {
            int it = tid + j * 512;
            if (it < 896) {
                int row = it / 28, ch = it - row * 28;
                int gr = bm + row;
                if (gr < M)
                    *(v8bf*)(HR + (size_t)gr * RSTRIDE + ch * 8) = *(const v8bf*)&T[row][ch * 8];
            }
        }
    } else {
        // fp32 output rows (stride DIMN)
        #pragma unroll
        for (int j = 0; j < 2; ++j) {
            int it = tid + j * 512;
            if (it < 800) {
                int row = it / 25, ch = it - row * 25;
                int gr = bm + row;
                if (gr < M) {
                    v8bf o = *(const v8bf*)&T[row][ch * 8];
                    float4* q0 = (float4*)(DoutF + (size_t)gr * DIMN + ch * 8);
                    q0[0] = make_float4((float)o[0], (float)o[1], (float)o[2], (float)o[3]);
                    q0[1] = make_float4((float)o[4], (float)o[5], (float)o[6], (float)o[7]);
                }
            }
        }
    }
}

extern "C" void kernel_launch(void* const* d_in, const int* in_sizes, int n_in,
                              void* d_out, int out_size, void* d_ws, size_t ws_size,
                              hipStream_t stream)
{
    const int*   edges = (const int*)  d_in[0];
    const float* ent   = (const float*)d_in[1];
    const float* relE  = (const float*)d_in[2];
    const float* Wm1   = (const float*)d_in[3];
    const float* Wl1   = (const float*)d_in[4];
    const float* Wm2   = (const float*)d_in[5];
    const float* Wl2   = (const float*)d_in[6];
    const float* Wtg   = (const float*)d_in[7];
    const float* bias  = (const float*)d_in[8];
    float* Dout = (float*)d_out;

    const size_t NM2 = (size_t)NNODES * RSTRIDE;

    __bf16* hR   = (__bf16*)d_ws;                      // h rows (stride 224)
    __bf16* SR   = hR + NM2;                           // S1/S2 rows
    __bf16* BR   = SR + NM2;                           // layer-1 out rows
    __bf16* RnR  = BR + NM2;                           // normalized relation rows
    __bf16* Wpk  = RnR + (size_t)NREL * RSTRIDE;       // 5 packed weights
    __bf16* pWm1 = Wpk + 0 * (size_t)WPK_ELEMS;
    __bf16* pWl1 = Wpk + 1 * (size_t)WPK_ELEMS;
    __bf16* pWm2 = Wpk + 2 * (size_t)WPK_ELEMS;
    __bf16* pWl2 = Wpk + 3 * (size_t)WPK_ELEMS;
    __bf16* pWtg = Wpk + 4 * (size_t)WPK_ELEMS;
    // batched CSR arrays over 3N super-nodes
    int*  counts = (int*)(Wpk + 5 * (size_t)WPK_ELEMS);
    int*  cursor = counts + TSTEPS * NNODES;
    int2* sorted = (int2*)(cursor + TSTEPS * NNODES);
    int*  offs   = (int*)(sorted + TSTEPS * NEDGES);
    int*  bsum   = offs + (TSTEPS * NNODES + 1);
    int*  stmp   = bsum + SCAN_B;

    dim3 blk(256);
    const int GD = (NNODES + 63) / 64;      // 1563 (dual, BM=64, 512 thr)
    const int GM = (NNODES + 31) / 32;      // 3125 (mega, BM=32, 512 thr)
    dim3 ngrid32((NNODES * 32 + 255) / 256);
    dim3 rgrid32((NREL * 32 + 255) / 256);
    dim3 agrid((NNODES + 3) / 4);
    dim3 egrid3((TSTEPS * NEDGES + 255) / 256);
    const int NTOT = TSTEPS * NNODES;               // 300000
    const int NSB  = (NTOT + SCAN_B - 1) / SCAN_B;  // 293

    // ---- weights + prologue norms ----
    pack_w<<<dim3((5 * KSTEPS * NB16 * 64 + 255) / 256), blk, 0, stream>>>(Wm1, Wl1, Wm2, Wl2, Wtg, Wpk);
    l2norm_pro<<<ngrid32, blk, 0, stream>>>(ent, hR, NNODES);
    l2norm_pro<<<rgrid32, blk, 0, stream>>>(relE, RnR, NREL);

    // ---- batched CSR build (all timesteps) ----
    hipMemsetAsync(counts, 0, 2 * NTOT * sizeof(int), stream);   // counts + cursor
    edge_hist3<<<egrid3, blk, 0, stream>>>(edges, counts);
    scan1<<<NSB, SCAN_B, 0, stream>>>(counts, stmp, bsum, NTOT);
    scan2<<<1, SCAN_B, 0, stream>>>(bsum, NSB);
    scan3<<<NSB, SCAN_B, 0, stream>>>(stmp, bsum, offs, NTOT);
    edge_fill3<<<egrid3, blk, 0, stream>>>(edges, offs, cursor, sorted);

    for (int t = 0; t < 3; ++t) {
        const int* offsT = offs + (size_t)t * NNODES;
        // ---- layer 1: aggregate in h-space, then dual-stream GEMM ----
        agg_S<<<agrid, blk, 0, stream>>>(offsT, sorted, hR, RnR, SR, NNODES);
        gemm_dual<<<GD, dim3(512), 0, stream>>>(SR, pWm1, hR, pWl1, BR, NNODES);
        // ---- layer 2 + gate + blend + norms (mega; HR in-place) ----
        agg_S<<<agrid, blk, 0, stream>>>(offsT, sorted, BR, RnR, SR, NNODES);
        gemm_mega<<<GM, dim3(512), 0, stream>>>(SR, pWm2, BR, pWl2, hR, pWtg, bias,
                                                Dout, NNODES, (t == 2) ? 1 : 0);
    }
}

// Round 14
// 819.629 us; speedup vs baseline: 1.9919x; 1.0468x over previous
//
#include <hip/hip_runtime.h>
#include <math.h>

#define DIMN    200
#define RSTRIDE 224          // padded row stride: 448B = 7 x 64B lines
#define NNODES  100000
#define NREL    500
#define NEDGES  200000
#define TSTEPS  3
#define KSTEPS  7            // K padded 200 -> 224 = 7*32
#define NB16    16           // N padded 200 -> 256
#define WPK_ELEMS (KSTEPS * NB16 * 64 * 8)   // 57344 bf16 per weight
#define SCAN_B  1024

typedef float  v4f  __attribute__((ext_vector_type(4)));
typedef __bf16 v8bf __attribute__((ext_vector_type(8)));

// R14: (a) dual merges 2 K-steps per barrier (8 barriers -> 5; each staged pair
// gets 2 steps of compute to land before its drain). Paired buffers = 32KB,
// still inside the 33.8KB T alias. (b) agg_S unrolled by 2 edges (independent
// gather chains -> 2x MLP on the serial L3-latency path). mega untouched (control).
#define GLOAD_LDS16(src, dst) \
    __builtin_amdgcn_global_load_lds((const __attribute__((address_space(1))) void*)(src), \
                                     (__attribute__((address_space(3))) void*)(dst), 16, 0, 0)

// ---------------- prologue l2norm: fp32 rows -> bf16 stride-224 rows (zero pad) ----------------
__launch_bounds__(256)
__global__ void l2norm_pro(const float* __restrict__ in, __bf16* __restrict__ out, int nrows)
{
    int idx  = blockIdx.x * 256 + threadIdx.x;
    int node = idx >> 5;
    int ch   = idx & 31;
    if (node >= nrows) return;
    float v[8] = {};
    if (ch < 25) {
        const float4* p = (const float4*)(in + (size_t)node * DIMN + ch * 8);
        float4 f0 = p[0], f1 = p[1];
        v[0]=f0.x; v[1]=f0.y; v[2]=f0.z; v[3]=f0.w;
        v[4]=f1.x; v[5]=f1.y; v[6]=f1.z; v[7]=f1.w;
    }
    float ss = 0.0f;
    #pragma unroll
    for (int k = 0; k < 8; ++k) ss += v[k] * v[k];
    #pragma unroll
    for (int off = 16; off; off >>= 1) ss += __shfl_xor(ss, off, 64);
    float s = 1.0f / fmaxf(sqrtf(ss), 1e-12f);
    if (ch < 28) {
        v8bf o;
        #pragma unroll
        for (int k = 0; k < 8; ++k) o[k] = (ch < 25) ? (__bf16)(v[k] * s) : (__bf16)0.0f;
        *(v8bf*)(out + (size_t)node * RSTRIDE + ch * 8) = o;
    }
}

// ---------------- batched CSR build over (t,node) super-nodes (R6 proven) ----------------
__launch_bounds__(256)
__global__ void edge_hist3(const int* __restrict__ edges, int* __restrict__ counts)
{
    int e = blockIdx.x * 256 + threadIdx.x;
    if (e < TSTEPS * NEDGES) {
        int t = e / NEDGES;
        atomicAdd(&counts[t * NNODES + edges[(size_t)e * 3 + 2]], 1);
    }
}

__launch_bounds__(SCAN_B)
__global__ void scan1(const int* __restrict__ counts, int* __restrict__ tmp,
                      int* __restrict__ bsum, int n)
{
    __shared__ int sh[SCAN_B];
    int i = blockIdx.x * SCAN_B + threadIdx.x;
    int v = (i < n) ? counts[i] : 0;
    sh[threadIdx.x] = v;
    __syncthreads();
    for (int off = 1; off < SCAN_B; off <<= 1) {
        int t = (threadIdx.x >= off) ? sh[threadIdx.x - off] : 0;
        __syncthreads();
        sh[threadIdx.x] += t;
        __syncthreads();
    }
    if (i < n) tmp[i] = sh[threadIdx.x];
    if (threadIdx.x == SCAN_B - 1) bsum[blockIdx.x] = sh[threadIdx.x];
}

__launch_bounds__(SCAN_B)
__global__ void scan2(int* __restrict__ bsum, int nb)
{
    __shared__ int sh[SCAN_B];
    int v = (threadIdx.x < nb) ? bsum[threadIdx.x] : 0;
    sh[threadIdx.x] = v;
    __syncthreads();
    for (int off = 1; off < SCAN_B; off <<= 1) {
        int t = (threadIdx.x >= off) ? sh[threadIdx.x - off] : 0;
        __syncthreads();
        sh[threadIdx.x] += t;
        __syncthreads();
    }
    if (threadIdx.x < nb) bsum[threadIdx.x] = sh[threadIdx.x] - v;
}

__launch_bounds__(SCAN_B)
__global__ void scan3(const int* __restrict__ tmp, const int* __restrict__ bsum,
                      int* __restrict__ offs, int n)
{
    int i = blockIdx.x * SCAN_B + threadIdx.x;
    if (i < n) offs[i + 1] = tmp[i] + bsum[blockIdx.x];
    if (i == 0) offs[0] = 0;
}

__launch_bounds__(256)
__global__ void edge_fill3(const int* __restrict__ edges, const int* __restrict__ offs,
                           int* __restrict__ cursor, int2* __restrict__ sorted)
{
    int e = blockIdx.x * 256 + threadIdx.x;
    if (e >= TSTEPS * NEDGES) return;
    int t = e / NEDGES;
    int s = edges[(size_t)e * 3 + 0];
    int r = edges[(size_t)e * 3 + 1];
    int d = edges[(size_t)e * 3 + 2];
    int sn = t * NNODES + d;
    int p = offs[sn] + atomicAdd(&cursor[sn], 1);
    sorted[p] = make_int2(s, r);
}

// ---------------- aggregate: S = segsum(x[src] + r[rel]) / max(deg,1) -> stride-224 rows ----------------
// R14: 2-edge unroll for MLP on the serial gather-latency chain.
__launch_bounds__(256)
__global__ void agg_S(const int* __restrict__ offs, const int2* __restrict__ sorted,
                      const __bf16* __restrict__ XR, const __bf16* __restrict__ RnR,
                      __bf16* __restrict__ SR, int nnodes)
{
    int wave = (int)((blockIdx.x * blockDim.x + threadIdx.x) >> 6);
    int lane = threadIdx.x & 63;
    if (wave >= nnodes) return;
    int beg = offs[wave], end = offs[wave + 1];
    int ch = lane & 31;
    bool act = ch < 25;

    float acc[8] = {};
    int e = beg;
    for (; e + 2 <= end; e += 2) {
        int2 sr0 = sorted[e];
        int2 sr1 = sorted[e + 1];
        const __bf16* b0 = (lane < 32) ? (XR + (size_t)sr0.x * RSTRIDE)
                                       : (RnR + (size_t)sr0.y * RSTRIDE);
        const __bf16* b1 = (lane < 32) ? (XR + (size_t)sr1.x * RSTRIDE)
                                       : (RnR + (size_t)sr1.y * RSTRIDE);
        v8bf v0 = {}, v1 = {};
        if (act) {
            v0 = *(const v8bf*)(b0 + ch * 8);
            v1 = *(const v8bf*)(b1 + ch * 8);
        }
        #pragma unroll
        for (int k = 0; k < 8; ++k) acc[k] += (float)v0[k] + (float)v1[k];
    }
    if (e < end) {
        int2 sr = sorted[e];
        const __bf16* base = (lane < 32) ? (XR + (size_t)sr.x * RSTRIDE)
                                         : (RnR + (size_t)sr.y * RSTRIDE);
        v8bf v = {};
        if (act) v = *(const v8bf*)(base + ch * 8);
        #pragma unroll
        for (int k = 0; k < 8; ++k) acc[k] += (float)v[k];
    }
    #pragma unroll
    for (int k = 0; k < 8; ++k) acc[k] += __shfl_xor(acc[k], 32, 64);

    float rdeg = 1.0f / fmaxf((float)(end - beg), 1.0f);
    if (lane < 32 && ch < 28) {
        v8bf o;
        #pragma unroll
        for (int k = 0; k < 8; ++k) o[k] = act ? (__bf16)(acc[k] * rdeg) : (__bf16)0.0f;
        *(v8bf*)(SR + (size_t)wave * RSTRIDE + ch * 8) = o;
    }
}

// ---------------- weight pack (R6 coalesced): chunk c = s*1024 + nb*64 + lane ----------------
__launch_bounds__(256)
__global__ void pack_w(const float* __restrict__ W0, const float* __restrict__ W1,
                       const float* __restrict__ W2, const float* __restrict__ W3,
                       const float* __restrict__ W4, __bf16* __restrict__ out)
{
    int id = blockIdx.x * 256 + threadIdx.x;
    const int nchunk = KSTEPS * NB16 * 64;        // 7168
    if (id >= 5 * nchunk) return;
    int wi = id / nchunk;
    int c  = id % nchunk;
    const float* W = wi == 0 ? W0 : wi == 1 ? W1 : wi == 2 ? W2 : wi == 3 ? W3 : W4;
    int s    = c >> 10;
    int nb   = (c & 1023) >> 6;
    int lane = c & 63;
    int kbase = s * 32 + (lane >> 4) * 8;
    int n     = nb * 16 + (lane & 15);
    __bf16* dst = out + (size_t)wi * WPK_ELEMS + (size_t)c * 8;
    #pragma unroll
    for (int j = 0; j < 8; ++j) {
        int k = kbase + j;
        float v = (k < DIMN && n < DIMN) ? W[k * DIMN + n] : 0.0f;
        dst[j] = (__bf16)v;
    }
}

// ---------------- G1: Out = A1@W1 + A2@W2 ; BM=64, 8 waves x ni=2 ----------------
// R14: 2 K-steps per barrier. As2[2 buf][2 sub][8][512] = 32KB aliased onto T.
__launch_bounds__(512)
__global__ void gemm_dual(const __bf16* __restrict__ A1, const __bf16* __restrict__ W1,
                          const __bf16* __restrict__ A2, const __bf16* __restrict__ W2,
                          __bf16* __restrict__ OutR, int M)
{
    const int tid  = threadIdx.x;
    const int w    = tid >> 6;          // 0..7
    const int lane = tid & 63;
    const int rlo  = lane & 15;
    const int g8   = lane >> 4;
    const int bm   = blockIdx.x * 64;

    __shared__ __bf16 shm[64 * 264];                         // 33.8KB
    __bf16 (*As)[2][8][512] = (__bf16(*)[2][8][512])shm;     // [2][2][8][512] = 32KB (K-loop only)
    __bf16 (*T)[264]        = (__bf16(*)[264])shm;           // [64][264] (post-loop only)

    v4f acc[4][2];
    #pragma unroll
    for (int mi = 0; mi < 4; ++mi)
        #pragma unroll
        for (int ni = 0; ni < 2; ++ni)
            acc[mi][ni] = (v4f){0.f, 0.f, 0.f, 0.f};

    // wave w stages chunk (stream = w>>2, nb = w&3); per-lane src row = bm+nb*16+rlo
    int rr = bm + (w & 3) * 16 + rlo;
    if (rr >= M) rr = M - 1;                                 // clamp: outputs masked on emit
    const __bf16* sb   = (w >> 2) == 0 ? A1 : A2;
    const __bf16* asrc = sb + (size_t)rr * RSTRIDE + g8 * 8;

    // coalesced B: wave w covers col blocks w*2+ni; lane-consecutive 16B
    const __bf16* w1b = W1 + (size_t)(w * 2 * 64 + lane) * 8;
    const __bf16* w2b = W2 + (size_t)(w * 2 * 64 + lane) * 8;

    // prologue: stage pair 0 (s = 0,1)
    GLOAD_LDS16(asrc,      &As[0][0][w][0]);
    GLOAD_LDS16(asrc + 32, &As[0][1][w][0]);
    __syncthreads();

    #pragma unroll
    for (int p = 0; p < 4; ++p) {
        // stage pair p+1 (pair 3 holds only s=6)
        if (p < 3) {
            GLOAD_LDS16(asrc + (2 * p + 2) * 32, &As[(p + 1) & 1][0][w][0]);
            if (p < 2)
                GLOAD_LDS16(asrc + (2 * p + 3) * 32, &As[(p + 1) & 1][1][w][0]);
        }
        #pragma unroll
        for (int u = 0; u < 2; ++u) {
            const int s = 2 * p + u;
            if (s < KSTEPS) {
                v8bf b1[2], b2[2];
                #pragma unroll
                for (int ni = 0; ni < 2; ++ni) {
                    size_t bo = ((size_t)s * NB16 * 64 + ni * 64) * 8;
                    b1[ni] = *(const v8bf*)(w1b + bo);
                    b2[ni] = *(const v8bf*)(w2b + bo);
                }
                #pragma unroll
                for (int mi = 0; mi < 4; ++mi) {
                    v8bf a1 = *(const v8bf*)&As[p & 1][u][mi][lane * 8];
                    v8bf a2 = *(const v8bf*)&As[p & 1][u][4 + mi][lane * 8];
                    #pragma unroll
                    for (int ni = 0; ni < 2; ++ni)
                        acc[mi][ni] = __builtin_amdgcn_mfma_f32_16x16x32_bf16(a1, b1[ni], acc[mi][ni], 0, 0, 0);
                    #pragma unroll
                    for (int ni = 0; ni < 2; ++ni)
                        acc[mi][ni] = __builtin_amdgcn_mfma_f32_16x16x32_bf16(a2, b2[ni], acc[mi][ni], 0, 0, 0);
                }
            }
        }
        __syncthreads();   // publish next pair; all reads of current done (also fences As->T reuse)
    }

    // D -> LDS tile (row = mi*16 + g8*4 + reg, col = w*32 + ni*16 + rlo); overwrites As region
    #pragma unroll
    for (int mi = 0; mi < 4; ++mi)
        #pragma unroll
        for (int reg = 0; reg < 4; ++reg)
            #pragma unroll
            for (int ni = 0; ni < 2; ++ni)
                T[mi * 16 + g8 * 4 + reg][w * 32 + ni * 16 + rlo] = (__bf16)acc[mi][ni][reg];
    __syncthreads();

    // row emit: 64 rows * 28 chunks = 1792 (cols 200-223 are zero via weight pad)
    #pragma unroll
    for (int j = 0; j < 4; ++j) {
        int it = tid + j * 512;
        if (it < 1792) {
            int row = it / 28, ch = it - row * 28;
            int gr = bm + row;
            if (gr < M)
                *(v8bf*)(OutR + (size_t)gr * RSTRIDE + ch * 8) = *(const v8bf*)&T[row][ch * 8];
        }
    }
}

// ---------------- G2 mega (R12 proven, UNCHANGED - control): ----------------
__launch_bounds__(512)
__global__ void gemm_mega(const __bf16* __restrict__ A1, const __bf16* __restrict__ W1,
                          const __bf16* __restrict__ A2, const __bf16* __restrict__ W2,
                          __bf16* __restrict__ HR, const __bf16* __restrict__ W3,
                          const float* __restrict__ Bias,
                          float* __restrict__ DoutF, int M, int finalStep)
{
    const int tid  = threadIdx.x;
    const int w    = tid >> 6;          // 0..7
    const int lane = tid & 63;
    const int rlo  = lane & 15;
    const int g8   = lane >> 4;
    const int bm   = blockIdx.x * 32;

    __shared__ __bf16 As[2][6][512];    // 12KB: chunk c = stream*2 + nb, dbuf
    __shared__ __bf16 T[32][264];
    __shared__ float  rsq1[32][8];
    __shared__ float  rsq2[32][8];

    v4f acc1[2][2], acc2[2][2];
    #pragma unroll
    for (int mi = 0; mi < 2; ++mi)
        #pragma unroll
        for (int ni = 0; ni < 2; ++ni) {
            acc1[mi][ni] = (v4f){0.f, 0.f, 0.f, 0.f};
            acc2[mi][ni] = (v4f){0.f, 0.f, 0.f, 0.f};
        }

    // staging source for issuing waves (w<6): stream = w>>1 in {A1,A2,HR}, nb = w&1
    const __bf16* sb   = (w >> 1) == 0 ? A1 : ((w >> 1) == 1 ? A2 : HR);
    const __bf16* asrc = sb + (size_t)(bm + (w & 1) * 16 + rlo) * RSTRIDE + g8 * 8;

    const __bf16* w1b = W1 + (size_t)(w * 2 * 64 + lane) * 8;
    const __bf16* w2b = W2 + (size_t)(w * 2 * 64 + lane) * 8;
    const __bf16* w3b = W3 + (size_t)(w * 2 * 64 + lane) * 8;

    // prologue: stage s=0 into buffer 0
    if (w < 6)
        GLOAD_LDS16(asrc, &As[0][w][0]);
    __syncthreads();    // drains issuer vmcnt; buffer 0 visible

    #pragma unroll
    for (int s = 0; s < KSTEPS; ++s) {
        if (s < KSTEPS - 1 && w < 6)
            GLOAD_LDS16(asrc + (s + 1) * 32, &As[(s + 1) & 1][w][0]);

        v8bf b1[2], b2[2], b3[2];
        #pragma unroll
        for (int ni = 0; ni < 2; ++ni) {
            size_t bo = ((size_t)s * NB16 * 64 + ni * 64) * 8;
            b1[ni] = *(const v8bf*)(w1b + bo);
            b2[ni] = *(const v8bf*)(w2b + bo);
            b3[ni] = *(const v8bf*)(w3b + bo);
        }
        #pragma unroll
        for (int mi = 0; mi < 2; ++mi) {
            v8bf a1 = *(const v8bf*)&As[s & 1][0 * 2 + mi][lane * 8];
            v8bf a2 = *(const v8bf*)&As[s & 1][1 * 2 + mi][lane * 8];
            v8bf a3 = *(const v8bf*)&As[s & 1][2 * 2 + mi][lane * 8];
            #pragma unroll
            for (int ni = 0; ni < 2; ++ni)
                acc1[mi][ni] = __builtin_amdgcn_mfma_f32_16x16x32_bf16(a1, b1[ni], acc1[mi][ni], 0, 0, 0);
            #pragma unroll
            for (int ni = 0; ni < 2; ++ni)
                acc1[mi][ni] = __builtin_amdgcn_mfma_f32_16x16x32_bf16(a2, b2[ni], acc1[mi][ni], 0, 0, 0);
            #pragma unroll
            for (int ni = 0; ni < 2; ++ni)
                acc2[mi][ni] = __builtin_amdgcn_mfma_f32_16x16x32_bf16(a3, b3[ni], acc2[mi][ni], 0, 0, 0);
        }
        __syncthreads();   // publish next buffer; all reads of current buffer done
    }

    // cur row sums-of-squares (cols >= 200 are zero via weight padding)
    #pragma unroll
    for (int mi = 0; mi < 2; ++mi)
        #pragma unroll
        for (int reg = 0; reg < 4; ++reg) {
            float ss = 0.0f;
            #pragma unroll
            for (int ni = 0; ni < 2; ++ni) ss += acc1[mi][ni][reg] * acc1[mi][ni][reg];
            ss += __shfl_xor(ss, 1, 64);
            ss += __shfl_xor(ss, 2, 64);
            ss += __shfl_xor(ss, 4, 64);
            ss += __shfl_xor(ss, 8, 64);
            if (rlo == 0) rsq1[mi * 16 + g8 * 4 + reg][w] = ss;
        }
    // stage h rows into T (overwritten only after blend completes)
    #pragma unroll
    for (int j = 0; j < 2; ++j) {
        int it = tid + j * 512;
        if (it < 800) {
            int row = it / 25, ch = it - row * 25;
            int gr = bm + row;
            v8bf hv = {};
            if (gr < M) hv = *(const v8bf*)(HR + (size_t)gr * RSTRIDE + ch * 8);
            *(v8bf*)&T[row][ch * 8] = hv;
        }
    }
    __syncthreads();

    // blend: v = gate*cur + (1-gate)*h  (store into acc1), second row reduce
    #pragma unroll
    for (int mi = 0; mi < 2; ++mi)
        #pragma unroll
        for (int reg = 0; reg < 4; ++reg) {
            int rl = mi * 16 + g8 * 4 + reg;
            float tot = rsq1[rl][0] + rsq1[rl][1] + rsq1[rl][2] + rsq1[rl][3]
                      + rsq1[rl][4] + rsq1[rl][5] + rsq1[rl][6] + rsq1[rl][7];
            float sc1 = 1.0f / fmaxf(sqrtf(tot), 1e-12f);
            float ss = 0.0f;
            #pragma unroll
            for (int ni = 0; ni < 2; ++ni) {
                int c = w * 32 + ni * 16 + rlo;
                float v = 0.0f;
                if (c < DIMN) {
                    float cur = acc1[mi][ni][reg] * sc1;
                    float gg  = 1.0f / (1.0f + __expf(-(acc2[mi][ni][reg] + Bias[c])));
                    float hh  = (float)T[rl][c];
                    v = gg * cur + (1.0f - gg) * hh;
                }
                acc1[mi][ni][reg] = v;
                ss += v * v;
            }
            ss += __shfl_xor(ss, 1, 64);
            ss += __shfl_xor(ss, 2, 64);
            ss += __shfl_xor(ss, 4, 64);
            ss += __shfl_xor(ss, 8, 64);
            if (rlo == 0) rsq2[rl][w] = ss;
        }
    __syncthreads();

    // final scale -> T (overwrites staged h; all h reads completed before barrier above)
    #pragma unroll
    for (int mi = 0; mi < 2; ++mi)
        #pragma unroll
        for (int reg = 0; reg < 4; ++reg) {
            int rl = mi * 16 + g8 * 4 + reg;
            float tot = rsq2[rl][0] + rsq2[rl][1] + rsq2[rl][2] + rsq2[rl][3]
                      + rsq2[rl][4] + rsq2[rl][5] + rsq2[rl][6] + rsq2[rl][7];
            float sc2 = 1.0f / fmaxf(sqrtf(tot), 1e-12f);
            #pragma unroll
            for (int ni = 0; ni < 2; ++ni) {
                int c = w * 32 + ni * 16 + rlo;
                T[rl][c] = (__bf16)(acc1[mi][ni][reg] * sc2);
            }
        }
    __syncthreads();

    if (!finalStep) {
        // h' rows: 32 rows * 28 chunks = 896 (cols 200-223 zero)
        #pragma unroll
        for (int j = 0; j < 2; ++j) {
            int it = tid + j * 512;
            if (it < 896) {
                int row = it / 28, ch = it - row * 28;
                int gr = bm + row;
                if (gr < M)
                    *(v8bf*)(HR + (size_t)gr * RSTRIDE + ch * 8) = *(const v8bf*)&T[row][ch * 8];
            }
        }
    } else {
        // fp32 output rows (stride DIMN)
        #pragma unroll
        for (int j = 0; j < 2; ++j) {
            int it = tid + j * 512;
            if (it < 800) {
                int row = it / 25, ch = it - row * 25;
                int gr = bm + row;
                if (gr < M) {
                    v8bf o = *(const v8bf*)&T[row][ch * 8];
                    float4* q0 = (float4*)(DoutF + (size_t)gr * DIMN + ch * 8);
                    q0[0] = make_float4((float)o[0], (float)o[1], (float)o[2], (float)o[3]);
                    q0[1] = make_float4((float)o[4], (float)o[5], (float)o[6], (float)o[7]);
                }
            }
        }
    }
}

extern "C" void kernel_launch(void* const* d_in, const int* in_sizes, int n_in,
                              void* d_out, int out_size, void* d_ws, size_t ws_size,
                              hipStream_t stream)
{
    const int*   edges = (const int*)  d_in[0];
    const float* ent   = (const float*)d_in[1];
    const float* relE  = (const float*)d_in[2];
    const float* Wm1   = (const float*)d_in[3];
    const float* Wl1   = (const float*)d_in[4];
    const float* Wm2   = (const float*)d_in[5];
    const float* Wl2   = (const float*)d_in[6];
    const float* Wtg   = (const float*)d_in[7];
    const float* bias  = (const float*)d_in[8];
    float* Dout = (float*)d_out;

    const size_t NM2 = (size_t)NNODES * RSTRIDE;

    __bf16* hR   = (__bf16*)d_ws;                      // h rows (stride 224)
    __bf16* SR   = hR + NM2;                           // S1/S2 rows
    __bf16* BR   = SR + NM2;                           // layer-1 out rows
    __bf16* RnR  = BR + NM2;                           // normalized relation rows
    __bf16* Wpk  = RnR + (size_t)NREL * RSTRIDE;       // 5 packed weights
    __bf16* pWm1 = Wpk + 0 * (size_t)WPK_ELEMS;
    __bf16* pWl1 = Wpk + 1 * (size_t)WPK_ELEMS;
    __bf16* pWm2 = Wpk + 2 * (size_t)WPK_ELEMS;
    __bf16* pWl2 = Wpk + 3 * (size_t)WPK_ELEMS;
    __bf16* pWtg = Wpk + 4 * (size_t)WPK_ELEMS;
    // batched CSR arrays over 3N super-nodes
    int*  counts = (int*)(Wpk + 5 * (size_t)WPK_ELEMS);
    int*  cursor = counts + TSTEPS * NNODES;
    int2* sorted = (int2*)(cursor + TSTEPS * NNODES);
    int*  offs   = (int*)(sorted + TSTEPS * NEDGES);
    int*  bsum   = offs + (TSTEPS * NNODES + 1);
    int*  stmp   = bsum + SCAN_B;

    dim3 blk(256);
    const int GD = (NNODES + 63) / 64;      // 1563 (dual, BM=64, 512 thr)
    const int GM = (NNODES + 31) / 32;      // 3125 (mega, BM=32, 512 thr)
    dim3 ngrid32((NNODES * 32 + 255) / 256);
    dim3 rgrid32((NREL * 32 + 255) / 256);
    dim3 agrid((NNODES + 3) / 4);
    dim3 egrid3((TSTEPS * NEDGES + 255) / 256);
    const int NTOT = TSTEPS * NNODES;               // 300000
    const int NSB  = (NTOT + SCAN_B - 1) / SCAN_B;  // 293

    // ---- weights + prologue norms ----
    pack_w<<<dim3((5 * KSTEPS * NB16 * 64 + 255) / 256), blk, 0, stream>>>(Wm1, Wl1, Wm2, Wl2, Wtg, Wpk);
    l2norm_pro<<<ngrid32, blk, 0, stream>>>(ent, hR, NNODES);
    l2norm_pro<<<rgrid32, blk, 0, stream>>>(relE, RnR, NREL);

    // ---- batched CSR build (all timesteps) ----
    hipMemsetAsync(counts, 0, 2 * NTOT * sizeof(int), stream);   // counts + cursor
    edge_hist3<<<egrid3, blk, 0, stream>>>(edges, counts);
    scan1<<<NSB, SCAN_B, 0, stream>>>(counts, stmp, bsum, NTOT);
    scan2<<<1, SCAN_B, 0, stream>>>(bsum, NSB);
    scan3<<<NSB, SCAN_B, 0, stream>>>(stmp, bsum, offs, NTOT);
    edge_fill3<<<egrid3, blk, 0, stream>>>(edges, offs, cursor, sorted);

    for (int t = 0; t < 3; ++t) {
        const int* offsT = offs + (size_t)t * NNODES;
        // ---- layer 1: aggregate in h-space, then dual-stream GEMM ----
        agg_S<<<agrid, blk, 0, stream>>>(offsT, sorted, hR, RnR, SR, NNODES);
        gemm_dual<<<GD, dim3(512), 0, stream>>>(SR, pWm1, hR, pWl1, BR, NNODES);
        // ---- layer 2 + gate + blend + norms (mega; HR in-place) ----
        agg_S<<<agrid, blk, 0, stream>>>(offsT, sorted, BR, RnR, SR, NNODES);
        gemm_mega<<<GM, dim3(512), 0, stream>>>(SR, pWm2, BR, pWl2, hR, pWtg, bias,
                                                Dout, NNODES, (t == 2) ? 1 : 0);
    }
}